// Round 1
// baseline (302.597 us; speedup 1.0000x reference)
//
#include <hip/hip_runtime.h>

typedef unsigned short u16;
typedef __attribute__((ext_vector_type(8))) __bf16 bf16x8;
typedef __attribute__((ext_vector_type(4))) float f32x4;
typedef __attribute__((ext_vector_type(4))) unsigned short u16x4;
typedef __attribute__((ext_vector_type(8))) unsigned short u16x8;

#define T_LEN 2048
#define B_SZ 4
#define E_DIM 1024
#define H_N 16
#define D_H 64
#define M_ROWS (T_LEN * B_SZ)   // 8192

__device__ __forceinline__ u16 f2bf(float f){
  unsigned u = __builtin_bit_cast(unsigned, f);
  u += 0x7fffu + ((u >> 16) & 1u);
  return (u16)(u >> 16);
}

__device__ __forceinline__ void load_lds16(const void* g, void* l){
  __builtin_amdgcn_global_load_lds(
      (const __attribute__((address_space(1))) void*)g,
      (__attribute__((address_space(3))) void*)l, 16, 0, 0);
}

// ---------------- fp32 -> bf16 convert ----------------
__global__ void cvt_bf16(const float* __restrict__ in, u16* __restrict__ out, int n){
  int idx = (blockIdx.x * blockDim.x + threadIdx.x) * 4;
  int stride = gridDim.x * blockDim.x * 4;
  for (int i = idx; i < n; i += stride){
    float4 v = *(const float4*)(in + i);
    u16x4 o = { f2bf(v.x), f2bf(v.y), f2bf(v.z), f2bf(v.w) };
    *(u16x4*)(out + i) = o;
  }
}

// ---------------- GEMM: C[m,n] = sum_k A[m,k] * Bt[n,k] + bias[n] ----------------
// EPI 0: m=(t*4+b) rows of [L,B,E]; write bf16 to [B,H,L,D]
// EPI 1: m=(b*2048+t) rows of AO [B,T,E]; write fp32 to d_out [T,B,E]
template<int EPI>
__global__ __launch_bounds__(256) void gemm_bt(
    const u16* __restrict__ A, const u16* __restrict__ Bt,
    const float* __restrict__ bias, u16* __restrict__ outB, float* __restrict__ outF)
{
  constexpr int K = E_DIM;
  __shared__ __align__(16) u16 As[128*32];
  __shared__ __align__(16) u16 Bs[128*32];
  const int tid = threadIdx.x;
  const int lane = tid & 63;
  const int w = tid >> 6;
  const int wr = w >> 1, wc = w & 1;
  const int lr = lane & 15, lg = lane >> 4;
  const int m0 = blockIdx.y * 128;
  const int n0 = blockIdx.x * 128;

  f32x4 acc[4][4];
  #pragma unroll
  for (int i=0;i<4;i++)
    #pragma unroll
    for (int j=0;j<4;j++) acc[i][j] = (f32x4){0.f,0.f,0.f,0.f};

  for (int k0 = 0; k0 < K; k0 += 32){
    __syncthreads();   // previous tile's reads complete
    #pragma unroll
    for (int r=0;r<2;++r){
      int c = r*256 + tid;
      int row = c >> 2, cc = (c & 3) * 8;
      load_lds16(A  + (size_t)(m0 + row)*K + k0 + cc,
                 (char*)As + (size_t)(r*256 + w*64)*16);
      load_lds16(Bt + (size_t)(n0 + row)*K + k0 + cc,
                 (char*)Bs + (size_t)(r*256 + w*64)*16);
    }
    __syncthreads();   // staging visible (compiler drains vmcnt before barrier)
    bf16x8 af[4], bfr[4];
    #pragma unroll
    for (int i=0;i<4;i++){
      af[i]  = *(const bf16x8*)&As[(wr*64 + i*16 + lr)*32 + lg*8];
      bfr[i] = *(const bf16x8*)&Bs[(wc*64 + i*16 + lr)*32 + lg*8];
    }
    #pragma unroll
    for (int i=0;i<4;i++)
      #pragma unroll
      for (int j=0;j<4;j++)
        acc[i][j] = __builtin_amdgcn_mfma_f32_16x16x32_bf16(af[i], bfr[j], acc[i][j], 0,0,0);
  }

  #pragma unroll
  for (int i=0;i<4;i++)
    #pragma unroll
    for (int j=0;j<4;j++)
      #pragma unroll
      for (int q=0;q<4;q++){
        int m = m0 + wr*64 + i*16 + lg*4 + q;
        int n = n0 + wc*64 + j*16 + lr;
        float v = acc[i][j][q] + bias[n];
        if (EPI == 0){
          int t = m >> 2, b = m & 3;             // rows of [L,B,E]: m = t*B + b
          int h = n >> 6, d = n & 63;
          outB[ ((size_t)(b*H_N + h)*T_LEN + t)*D_H + d ] = f2bf(v);
        } else {
          int b = m >> 11, t = m & 2047;         // rows of AO [B,T,E]: m = b*T + t
          outF[ (size_t)(t*B_SZ + b)*E_DIM + n ] = v;
        }
      }
}

// ---------------- V transpose: [B,H,S,D] -> [B,H,D,S] ----------------
__global__ __launch_bounds__(256) void transpose_v(const u16* __restrict__ Vb, u16* __restrict__ Vt){
  __shared__ u16 tile[64][72];
  int bh = blockIdx.y, s0 = blockIdx.x * 64;
  const u16* src = Vb + ((size_t)bh*T_LEN + s0)*D_H;
  u16* dst = Vt + (size_t)bh*D_H*T_LEN + s0;
  int tid = threadIdx.x;
  #pragma unroll
  for (int r=0;r<2;++r){
    int c = r*256 + tid;
    int s = c >> 3, d0 = (c & 7)*8;
    u16x8 v = *(const u16x8*)(src + (size_t)s*D_H + d0);
    #pragma unroll
    for (int j=0;j<8;j++) tile[d0+j][s] = v[j];
  }
  __syncthreads();
  #pragma unroll
  for (int r=0;r<2;++r){
    int c = r*256 + tid;
    int d = c >> 3, s1 = (c & 7)*8;
    u16x8 v;
    #pragma unroll
    for (int j=0;j<8;j++) v[j] = tile[d][s1+j];
    *(u16x8*)(dst + (size_t)d*T_LEN + s1) = v;
  }
}

// ---------------- causal flash attention ----------------
// Qb [B,H,T,D], Kb [B,H,S,D], Vt [B,H,D,S] (all bf16) -> AO [B,T,E] bf16
__global__ __launch_bounds__(256) void attn_fwd(
    const u16* __restrict__ Qb, const u16* __restrict__ Kb,
    const u16* __restrict__ Vt, u16* __restrict__ AO)
{
  __shared__ __align__(16) u16 Ks[64*64];   // swizzled [s][d]
  __shared__ __align__(16) u16 Vs[64*64];   // swizzled [d][s]
  __shared__ __align__(16) u16 Ps[64*72];   // [q][s], stride 72
  const int tid = threadIdx.x;
  const int lane = tid & 63;
  const int wq = tid >> 6;                  // wave's q sub-block (16 rows each)
  const int lr = lane & 15, lg = lane >> 4;
  const int bh = blockIdx.y;                // b*H + h
  const int qb = blockIdx.x * 64;
  const size_t headQ = (size_t)bh * T_LEN * D_H;
  const size_t headV = (size_t)bh * D_H * T_LEN;

  // Q fragments in registers: Q[qb + wq*16 + lr][lg*8 + ks*32 + j]
  bf16x8 qf[2];
  {
    const u16* qp = Qb + headQ + (size_t)(qb + wq*16 + lr)*D_H + lg*8;
    qf[0] = *(const bf16x8*)qp;
    qf[1] = *(const bf16x8*)(qp + 32);
  }

  f32x4 o[4];
  #pragma unroll
  for (int f=0;f<4;f++) o[f] = (f32x4){0.f,0.f,0.f,0.f};
  float m_run = -INFINITY, l_run = 0.f;

  const int ntiles = blockIdx.x + 1;        // causal
  for (int kt = 0; kt < ntiles; ++kt){
    int s0 = kt * 64;
    // stage K tile and Vt tile (linear LDS dst, pre-swizzled global src)
    #pragma unroll
    for (int r=0;r<2;++r){
      int c = r*256 + tid;
      int row = c >> 3;
      int colb = (c & 7) * 16;
      int scolb = colb ^ ((row & 7) << 4);
      load_lds16((const char*)(Kb + headQ + (size_t)(s0 + row)*D_H) + scolb,
                 (char*)Ks + (size_t)(r*256 + wq*64)*16);
      load_lds16((const char*)(Vt + headV + (size_t)row*T_LEN + s0) + scolb,
                 (char*)Vs + (size_t)(r*256 + wq*64)*16);
    }
    __syncthreads();

    // S^T = K · Q^T : st[f] holds S^T[s = f*16 + lg*4 + q][q_loc = wq*16 + lr]
    f32x4 st[4];
    #pragma unroll
    for (int f=0; f<4; ++f){
      st[f] = (f32x4){0.f,0.f,0.f,0.f};
      #pragma unroll
      for (int ks=0; ks<2; ++ks){
        int srow = f*16 + lr;
        int colb = (lg*8 + ks*32)*2;
        int scolb = colb ^ ((srow & 7) << 4);
        bf16x8 kf = *(const bf16x8*)((const char*)Ks + srow*128 + scolb);
        st[f] = __builtin_amdgcn_mfma_f32_16x16x32_bf16(kf, qf[ks], st[f], 0,0,0);
      }
    }

    // scale + causal mask + online softmax
    const bool diag = (kt == blockIdx.x);
    float mx = -INFINITY;
    #pragma unroll
    for (int f=0; f<4; ++f)
      #pragma unroll
      for (int q=0; q<4; ++q){
        float v = st[f][q] * 0.125f;
        if (diag){
          int sl = f*16 + lg*4 + q;
          int ql = wq*16 + lr;
          if (sl > ql) v = -INFINITY;
        }
        st[f][q] = v;
        mx = fmaxf(mx, v);
      }
    mx = fmaxf(mx, __shfl_xor(mx, 16));
    mx = fmaxf(mx, __shfl_xor(mx, 32));
    float m_new = fmaxf(m_run, mx);
    float scale = __expf(m_run - m_new);
    float rsum = 0.f;
    #pragma unroll
    for (int f=0;f<4;++f)
      #pragma unroll
      for (int q=0;q<4;++q){
        float p = __expf(st[f][q] - m_new);
        st[f][q] = p;
        rsum += p;
      }
    rsum += __shfl_xor(rsum, 16);
    rsum += __shfl_xor(rsum, 32);
    l_run = l_run * scale + rsum;
    m_run = m_new;

    // rescale O (O rows are q = lg*4 + q; stats live at lane (l&15)==q)
    #pragma unroll
    for (int q=0; q<4; ++q){
      float fq = __shfl(scale, lg*4 + q);
      #pragma unroll
      for (int f=0; f<4; ++f) o[f][q] *= fq;
    }

    // P -> LDS (bf16), layout [q_loc][s] stride 72 (per-wave private rows)
    #pragma unroll
    for (int f=0;f<4;++f)
      #pragma unroll
      for (int q=0;q<4;++q){
        int sl = f*16 + lg*4 + q;
        Ps[(wq*16 + lr)*72 + sl] = f2bf(st[f][q]);
      }

    // O += P · V
    #pragma unroll
    for (int ks=0; ks<2; ++ks){
      bf16x8 pf = *(const bf16x8*)&Ps[(wq*16 + lr)*72 + ks*32 + lg*8];
      #pragma unroll
      for (int f=0; f<4; ++f){
        int drow = f*16 + lr;
        int colb = (lg*8 + ks*32)*2;
        int scolb = colb ^ ((drow & 7) << 4);
        bf16x8 vf = *(const bf16x8*)((const char*)Vs + drow*128 + scolb);
        o[f] = __builtin_amdgcn_mfma_f32_16x16x32_bf16(pf, vf, o[f], 0,0,0);
      }
    }
    __syncthreads();   // reads done before next tile's staging
  }

  // normalize + write AO [B,T,E]
  float linv[4];
  #pragma unroll
  for (int q=0;q<4;++q) linv[q] = 1.f / __shfl(l_run, lg*4 + q);
  const int b = bh >> 4, h = bh & 15;
  #pragma unroll
  for (int f=0;f<4;++f)
    #pragma unroll
    for (int q=0;q<4;++q){
      int qg = qb + wq*16 + lg*4 + q;
      int d = f*16 + lr;
      AO[ ((size_t)(b*T_LEN + qg))*E_DIM + h*D_H + d ] = f2bf(o[f][q] * linv[q]);
    }
}

extern "C" void kernel_launch(void* const* d_in, const int* in_sizes, int n_in,
                              void* d_out, int out_size, void* d_ws, size_t ws_size,
                              hipStream_t stream){
  const float* query = (const float*)d_in[0];
  const float* key   = (const float*)d_in[1];
  const float* value = (const float*)d_in[2];
  // d_in[3] = attn_mask (causal, known statically) — unused
  const float* Wq = (const float*)d_in[4];
  const float* bq = (const float*)d_in[5];
  const float* Wk = (const float*)d_in[6];
  const float* bk = (const float*)d_in[7];
  const float* Wv = (const float*)d_in[8];
  const float* bv = (const float*)d_in[9];
  const float* Wo = (const float*)d_in[10];
  const float* bo = (const float*)d_in[11];

  char* ws = (char*)d_ws;
  const size_t SZ_X = (size_t)M_ROWS * E_DIM * 2;   // 16 MB
  const size_t SZ_W = (size_t)E_DIM * E_DIM * 2;    // 2 MB
  u16* Xq  = (u16*)(ws);                    // reused as AO after Q-proj
  u16* Xk  = (u16*)(ws + SZ_X);             // reused as Vt after K-proj
  u16* Xv  = (u16*)(ws + 2*SZ_X);
  u16* Wqb = (u16*)(ws + 3*SZ_X);
  u16* Wkb = (u16*)(ws + 3*SZ_X + 1*SZ_W);
  u16* Wvb = (u16*)(ws + 3*SZ_X + 2*SZ_W);
  u16* Wob = (u16*)(ws + 3*SZ_X + 3*SZ_W);
  u16* Qb  = (u16*)(ws + 3*SZ_X + 4*SZ_W);
  u16* Kb  = (u16*)(ws + 4*SZ_X + 4*SZ_W);
  u16* Vb  = (u16*)(ws + 5*SZ_X + 4*SZ_W);
  u16* Vt  = Xk;
  u16* AO  = Xq;

  const int nX = M_ROWS * E_DIM;
  const int nW = E_DIM * E_DIM;
  cvt_bf16<<<2048, 256, 0, stream>>>(query, Xq, nX);
  cvt_bf16<<<2048, 256, 0, stream>>>(key,   Xk, nX);
  cvt_bf16<<<2048, 256, 0, stream>>>(value, Xv, nX);
  cvt_bf16<<<1024, 256, 0, stream>>>(Wq, Wqb, nW);
  cvt_bf16<<<1024, 256, 0, stream>>>(Wk, Wkb, nW);
  cvt_bf16<<<1024, 256, 0, stream>>>(Wv, Wvb, nW);
  cvt_bf16<<<1024, 256, 0, stream>>>(Wo, Wob, nW);

  dim3 gg(E_DIM/128, M_ROWS/128);
  gemm_bt<0><<<gg, 256, 0, stream>>>(Xq, Wqb, bq, Qb, nullptr);
  gemm_bt<0><<<gg, 256, 0, stream>>>(Xk, Wkb, bk, Kb, nullptr);
  gemm_bt<0><<<gg, 256, 0, stream>>>(Xv, Wvb, bv, Vb, nullptr);
  transpose_v<<<dim3(T_LEN/64, B_SZ*H_N), 256, 0, stream>>>(Vb, Vt);
  attn_fwd<<<dim3(T_LEN/64, B_SZ*H_N), 256, 0, stream>>>(Qb, Kb, Vt, AO);
  gemm_bt<1><<<gg, 256, 0, stream>>>(AO, Wob, bo, nullptr, (float*)d_out);
}

// Round 2
// 270.369 us; speedup vs baseline: 1.1192x; 1.1192x over previous
//
#include <hip/hip_runtime.h>

typedef unsigned short u16;
typedef __attribute__((ext_vector_type(8))) __bf16 bf16x8;
typedef __attribute__((ext_vector_type(4))) float f32x4;
typedef __attribute__((ext_vector_type(4))) unsigned short u16x4;
typedef __attribute__((ext_vector_type(8))) unsigned short u16x8;

#define T_LEN 2048
#define B_SZ 4
#define E_DIM 1024
#define H_N 16
#define D_H 64
#define M_ROWS (T_LEN * B_SZ)   // 8192

__device__ __forceinline__ u16 f2bf(float f){
  unsigned u = __builtin_bit_cast(unsigned, f);
  u += 0x7fffu + ((u >> 16) & 1u);
  return (u16)(u >> 16);
}

__device__ __forceinline__ float fexp2(float x){
#if __has_builtin(__builtin_amdgcn_exp2f)
  return __builtin_amdgcn_exp2f(x);
#else
  return exp2f(x);
#endif
}

__device__ __forceinline__ void load_lds16(const void* g, void* l){
  __builtin_amdgcn_global_load_lds(
      (const __attribute__((address_space(1))) void*)g,
      (__attribute__((address_space(3))) void*)l, 16, 0, 0);
}

// ---------------- fp32 -> bf16 convert, all 7 tensors in one launch ----------------
__global__ void cvt_all(
    const float* __restrict__ i0, const float* __restrict__ i1, const float* __restrict__ i2,
    const float* __restrict__ i3, const float* __restrict__ i4, const float* __restrict__ i5,
    const float* __restrict__ i6,
    u16* __restrict__ o0, u16* __restrict__ o1, u16* __restrict__ o2,
    u16* __restrict__ o3, u16* __restrict__ o4, u16* __restrict__ o5,
    u16* __restrict__ o6, int nX, int nW)
{
  const int z = blockIdx.z;
  const float* in; u16* out; int n;
  switch (z){
    case 0: in=i0; out=o0; n=nX; break;
    case 1: in=i1; out=o1; n=nX; break;
    case 2: in=i2; out=o2; n=nX; break;
    case 3: in=i3; out=o3; n=nW; break;
    case 4: in=i4; out=o4; n=nW; break;
    case 5: in=i5; out=o5; n=nW; break;
    default: in=i6; out=o6; n=nW; break;
  }
  int idx = (blockIdx.x * blockDim.x + threadIdx.x) * 4;
  int stride = gridDim.x * blockDim.x * 4;
  for (int i = idx; i < n; i += stride){
    float4 v = *(const float4*)(in + i);
    u16x4 o = { f2bf(v.x), f2bf(v.y), f2bf(v.z), f2bf(v.w) };
    *(u16x4*)(out + i) = o;
  }
}

// ---------------- GEMM: C[m,n] = (sum_k A[m,k]*Bt[n,k] + bias[n]) * scale ----------------
// EPI 0: m=(t*4+b) rows of [L,B,E]; write bf16 to [B,H,L,D]
// EPI 1: m=(b*2048+t) rows of AO [B,T,E]; write fp32 to d_out [T,B,E]
template<int EPI>
__global__ __launch_bounds__(256) void gemm_bt(
    const u16* __restrict__ A, const u16* __restrict__ Bt,
    const float* __restrict__ bias, float scale,
    u16* __restrict__ outB, float* __restrict__ outF)
{
  constexpr int K = E_DIM;
  __shared__ __align__(16) u16 As[128*32];
  __shared__ __align__(16) u16 Bs[128*32];
  const int tid = threadIdx.x;
  const int lane = tid & 63;
  const int w = tid >> 6;
  const int wr = w >> 1, wc = w & 1;
  const int lr = lane & 15, lg = lane >> 4;
  const int m0 = blockIdx.y * 128;
  const int n0 = blockIdx.x * 128;

  f32x4 acc[4][4];
  #pragma unroll
  for (int i=0;i<4;i++)
    #pragma unroll
    for (int j=0;j<4;j++) acc[i][j] = (f32x4){0.f,0.f,0.f,0.f};

  for (int k0 = 0; k0 < K; k0 += 32){
    __syncthreads();
    #pragma unroll
    for (int r=0;r<2;++r){
      int c = r*256 + tid;
      int row = c >> 2, cc = (c & 3) * 8;
      load_lds16(A  + (size_t)(m0 + row)*K + k0 + cc,
                 (char*)As + (size_t)(r*256 + w*64)*16);
      load_lds16(Bt + (size_t)(n0 + row)*K + k0 + cc,
                 (char*)Bs + (size_t)(r*256 + w*64)*16);
    }
    __syncthreads();
    bf16x8 af[4], bfr[4];
    #pragma unroll
    for (int i=0;i<4;i++){
      af[i]  = *(const bf16x8*)&As[(wr*64 + i*16 + lr)*32 + lg*8];
      bfr[i] = *(const bf16x8*)&Bs[(wc*64 + i*16 + lr)*32 + lg*8];
    }
    #pragma unroll
    for (int i=0;i<4;i++)
      #pragma unroll
      for (int j=0;j<4;j++)
        acc[i][j] = __builtin_amdgcn_mfma_f32_16x16x32_bf16(af[i], bfr[j], acc[i][j], 0,0,0);
  }

  #pragma unroll
  for (int i=0;i<4;i++)
    #pragma unroll
    for (int j=0;j<4;j++)
      #pragma unroll
      for (int q=0;q<4;q++){
        int m = m0 + wr*64 + i*16 + lg*4 + q;
        int n = n0 + wc*64 + j*16 + lr;
        float v = (acc[i][j][q] + bias[n]) * scale;
        if (EPI == 0){
          int t = m >> 2, b = m & 3;             // rows of [L,B,E]: m = t*B + b
          int h = n >> 6, d = n & 63;
          outB[ ((size_t)(b*H_N + h)*T_LEN + t)*D_H + d ] = f2bf(v);
        } else {
          int b = m >> 11, t = m & 2047;         // rows of AO [B,T,E]: m = b*T + t
          outF[ (size_t)(t*B_SZ + b)*E_DIM + n ] = v;
        }
      }
}

// ---------------- V transpose: [B,H,S,D] -> [B,H,D,S] ----------------
__global__ __launch_bounds__(256) void transpose_v(const u16* __restrict__ Vb, u16* __restrict__ Vt){
  __shared__ u16 tile[64][72];
  int bh = blockIdx.y, s0 = blockIdx.x * 64;
  const u16* src = Vb + ((size_t)bh*T_LEN + s0)*D_H;
  u16* dst = Vt + (size_t)bh*D_H*T_LEN + s0;
  int tid = threadIdx.x;
  #pragma unroll
  for (int r=0;r<2;++r){
    int c = r*256 + tid;
    int s = c >> 3, d0 = (c & 7)*8;
    u16x8 v = *(const u16x8*)(src + (size_t)s*D_H + d0);
    #pragma unroll
    for (int j=0;j<8;j++) tile[d0+j][s] = v[j];
  }
  __syncthreads();
  #pragma unroll
  for (int r=0;r<2;++r){
    int c = r*256 + tid;
    int d = c >> 3, s1 = (c & 7)*8;
    u16x8 v;
    #pragma unroll
    for (int j=0;j<8;j++) v[j] = tile[d][s1+j];
    *(u16x8*)(dst + (size_t)d*T_LEN + s1) = v;
  }
}

// ---------------- causal flash attention ----------------
// Qb [B,H,T,D] (pre-scaled by 0.125*log2e), Kb [B,H,S,D], Vt [B,H,D,S] -> AO [B,T,E] bf16
// Scores live in log2 domain: p = 2^(s - m).
__global__ __launch_bounds__(256) void attn_fwd(
    const u16* __restrict__ Qb, const u16* __restrict__ Kb,
    const u16* __restrict__ Vt, u16* __restrict__ AO)
{
  __shared__ __align__(16) u16 Ks[64*64];   // swizzled [s][d]
  __shared__ __align__(16) u16 Vs[64*64];   // swizzled [d][s]
  __shared__ __align__(16) u16 Ps[64*72];   // [q][s], stride 72
  const int tid = threadIdx.x;
  const int lane = tid & 63;
  const int wq = tid >> 6;
  const int lr = lane & 15, lg = lane >> 4;
  const int bh = blockIdx.y;
  const int qt = gridDim.x - 1 - blockIdx.x;  // reversed: heavy blocks dispatch first
  const int qb = qt * 64;
  const size_t headQ = (size_t)bh * T_LEN * D_H;
  const size_t headV = (size_t)bh * D_H * T_LEN;

  bf16x8 qf[2];
  {
    const u16* qp = Qb + headQ + (size_t)(qb + wq*16 + lr)*D_H + lg*8;
    qf[0] = *(const bf16x8*)qp;
    qf[1] = *(const bf16x8*)(qp + 32);
  }

  f32x4 o[4];
  #pragma unroll
  for (int f=0;f<4;f++) o[f] = (f32x4){0.f,0.f,0.f,0.f};
  float m_run = -INFINITY, l_run = 0.f;

  const int ntiles = qt + 1;
  for (int kt = 0; kt < ntiles; ++kt){
    int s0 = kt * 64;
    #pragma unroll
    for (int r=0;r<2;++r){
      int c = r*256 + tid;
      int row = c >> 3;
      int colb = (c & 7) * 16;
      int scolb = colb ^ ((row & 7) << 4);
      load_lds16((const char*)(Kb + headQ + (size_t)(s0 + row)*D_H) + scolb,
                 (char*)Ks + (size_t)(r*256 + wq*64)*16);
      load_lds16((const char*)(Vt + headV + (size_t)row*T_LEN + s0) + scolb,
                 (char*)Vs + (size_t)(r*256 + wq*64)*16);
    }
    __syncthreads();

    // S^T = K · Q^T : st[f][q] = S^T[s = f*16 + lg*4 + q][q_loc = wq*16 + lr]  (log2 units)
    f32x4 st[4];
    #pragma unroll
    for (int f=0; f<4; ++f){
      st[f] = (f32x4){0.f,0.f,0.f,0.f};
      #pragma unroll
      for (int ks=0; ks<2; ++ks){
        int srow = f*16 + lr;
        int colb = (lg*8 + ks*32)*2;
        int scolb = colb ^ ((lr & 7) << 4);   // (srow&7)==(lr&7) since f*16 ≡ 0 mod 8
        bf16x8 kf = *(const bf16x8*)((const char*)Ks + srow*128 + scolb);
        st[f] = __builtin_amdgcn_mfma_f32_16x16x32_bf16(kf, qf[ks], st[f], 0,0,0);
      }
    }

    // causal mask (diagonal tile only) + row max
    const bool diag = (kt == qt);
    float mx = -INFINITY;
    if (diag){
      #pragma unroll
      for (int f=0; f<4; ++f)
        #pragma unroll
        for (int q=0; q<4; ++q){
          int sl = f*16 + lg*4 + q;
          int ql = wq*16 + lr;
          float v = (sl > ql) ? -INFINITY : st[f][q];
          st[f][q] = v;
          mx = fmaxf(mx, v);
        }
    } else {
      #pragma unroll
      for (int f=0; f<4; ++f)
        #pragma unroll
        for (int q=0; q<4; ++q) mx = fmaxf(mx, st[f][q]);
    }
    mx = fmaxf(mx, __shfl_xor(mx, 16));
    mx = fmaxf(mx, __shfl_xor(mx, 32));

    // defer-max: skip O-rescale while the running max is still adequate (P bounded by 2^8)
    if (!__all(mx <= m_run + 8.0f)){
      float m_new = fmaxf(m_run, mx);
      float sc = fexp2(m_run - m_new);
      l_run *= sc;
      #pragma unroll
      for (int q=0; q<4; ++q){
        float fq = __shfl(sc, lg*4 + q);
        #pragma unroll
        for (int f=0; f<4; ++f) o[f][q] *= fq;
      }
      m_run = m_new;
    }

    float rsum = 0.f;
    #pragma unroll
    for (int f=0;f<4;++f)
      #pragma unroll
      for (int q=0;q<4;++q){
        float p = fexp2(st[f][q] - m_run);
        st[f][q] = p;
        rsum += p;
      }
    rsum += __shfl_xor(rsum, 16);
    rsum += __shfl_xor(rsum, 32);
    l_run += rsum;

    // P -> LDS (bf16, hw cvt), vectorized 4-wide stores; rows are per-wave private
    #pragma unroll
    for (int f=0;f<4;++f){
      u16x4 pk;
      #pragma unroll
      for (int q=0;q<4;++q) pk[q] = __builtin_bit_cast(u16, (__bf16)st[f][q]);
      *(u16x4*)&Ps[(wq*16 + lr)*72 + f*16 + lg*4] = pk;
    }

    // O += P · V
    #pragma unroll
    for (int ks=0; ks<2; ++ks){
      bf16x8 pf = *(const bf16x8*)&Ps[(wq*16 + lr)*72 + ks*32 + lg*8];
      #pragma unroll
      for (int f=0; f<4; ++f){
        int drow = f*16 + lr;
        int colb = (lg*8 + ks*32)*2;
        int scolb = colb ^ ((lr & 7) << 4);
        bf16x8 vf = *(const bf16x8*)((const char*)Vs + drow*128 + scolb);
        o[f] = __builtin_amdgcn_mfma_f32_16x16x32_bf16(pf, vf, o[f], 0,0,0);
      }
    }
    __syncthreads();
  }

  float linv[4];
  #pragma unroll
  for (int q=0;q<4;++q) linv[q] = 1.f / __shfl(l_run, lg*4 + q);
  const int b = bh >> 4, h = bh & 15;
  #pragma unroll
  for (int f=0;f<4;++f)
    #pragma unroll
    for (int q=0;q<4;++q){
      int qg = qb + wq*16 + lg*4 + q;
      int d = f*16 + lr;
      AO[ ((size_t)(b*T_LEN + qg))*E_DIM + h*D_H + d ] = f2bf(o[f][q] * linv[q]);
    }
}

extern "C" void kernel_launch(void* const* d_in, const int* in_sizes, int n_in,
                              void* d_out, int out_size, void* d_ws, size_t ws_size,
                              hipStream_t stream){
  const float* query = (const float*)d_in[0];
  const float* key   = (const float*)d_in[1];
  const float* value = (const float*)d_in[2];
  const float* Wq = (const float*)d_in[4];
  const float* bq = (const float*)d_in[5];
  const float* Wk = (const float*)d_in[6];
  const float* bk = (const float*)d_in[7];
  const float* Wv = (const float*)d_in[8];
  const float* bv = (const float*)d_in[9];
  const float* Wo = (const float*)d_in[10];
  const float* bo = (const float*)d_in[11];

  char* ws = (char*)d_ws;
  const size_t SZ_X = (size_t)M_ROWS * E_DIM * 2;   // 16 MB
  const size_t SZ_W = (size_t)E_DIM * E_DIM * 2;    // 2 MB
  u16* Xq  = (u16*)(ws);                    // reused as AO after Q-proj
  u16* Xk  = (u16*)(ws + SZ_X);             // reused as Vt after K-proj
  u16* Xv  = (u16*)(ws + 2*SZ_X);
  u16* Wqb = (u16*)(ws + 3*SZ_X);
  u16* Wkb = (u16*)(ws + 3*SZ_X + 1*SZ_W);
  u16* Wvb = (u16*)(ws + 3*SZ_X + 2*SZ_W);
  u16* Wob = (u16*)(ws + 3*SZ_X + 3*SZ_W);
  u16* Qb  = (u16*)(ws + 3*SZ_X + 4*SZ_W);
  u16* Kb  = (u16*)(ws + 4*SZ_X + 4*SZ_W);
  u16* Vb  = (u16*)(ws + 5*SZ_X + 4*SZ_W);
  u16* Vt  = Xk;
  u16* AO  = Xq;

  const int nX = M_ROWS * E_DIM;
  const int nW = E_DIM * E_DIM;
  cvt_all<<<dim3(1024,1,7), 256, 0, stream>>>(
      query, key, value, Wq, Wk, Wv, Wo,
      Xq, Xk, Xv, Wqb, Wkb, Wvb, Wob, nX, nW);

  const float QSCALE = 0.125f * 1.44269504f;   // 1/sqrt(D) * log2(e): scores in log2 domain
  dim3 gg(E_DIM/128, M_ROWS/128);
  gemm_bt<0><<<gg, 256, 0, stream>>>(Xq, Wqb, bq, QSCALE, Qb, nullptr);
  gemm_bt<0><<<gg, 256, 0, stream>>>(Xk, Wkb, bk, 1.0f,   Kb, nullptr);
  gemm_bt<0><<<gg, 256, 0, stream>>>(Xv, Wvb, bv, 1.0f,   Vb, nullptr);
  transpose_v<<<dim3(T_LEN/64, B_SZ*H_N), 256, 0, stream>>>(Vb, Vt);
  attn_fwd<<<dim3(T_LEN/64, B_SZ*H_N), 256, 0, stream>>>(Qb, Kb, Vt, AO);
  gemm_bt<1><<<gg, 256, 0, stream>>>(AO, Wob, bo, 1.0f, nullptr, (float*)d_out);
}

// Round 3
// 263.702 us; speedup vs baseline: 1.1475x; 1.0253x over previous
//
#include <hip/hip_runtime.h>

typedef unsigned short u16;
typedef __attribute__((ext_vector_type(8))) __bf16 bf16x8;
typedef __attribute__((ext_vector_type(4))) float f32x4;
typedef __attribute__((ext_vector_type(4))) unsigned short u16x4;
typedef __attribute__((ext_vector_type(8))) unsigned short u16x8;

#define T_LEN 2048
#define B_SZ 4
#define E_DIM 1024
#define H_N 16
#define D_H 64
#define M_ROWS (T_LEN * B_SZ)   // 8192

__device__ __forceinline__ u16 f2bf(float f){
  unsigned u = __builtin_bit_cast(unsigned, f);
  u += 0x7fffu + ((u >> 16) & 1u);
  return (u16)(u >> 16);
}

__device__ __forceinline__ float fexp2(float x){
#if __has_builtin(__builtin_amdgcn_exp2f)
  return __builtin_amdgcn_exp2f(x);
#else
  return exp2f(x);
#endif
}

__device__ __forceinline__ void load_lds16(const void* g, void* l){
  __builtin_amdgcn_global_load_lds(
      (const __attribute__((address_space(1))) void*)g,
      (__attribute__((address_space(3))) void*)l, 16, 0, 0);
}

// ---------------- fp32 -> bf16 convert, all 7 tensors in one launch ----------------
__global__ void cvt_all(
    const float* __restrict__ i0, const float* __restrict__ i1, const float* __restrict__ i2,
    const float* __restrict__ i3, const float* __restrict__ i4, const float* __restrict__ i5,
    const float* __restrict__ i6,
    u16* __restrict__ o0, u16* __restrict__ o1, u16* __restrict__ o2,
    u16* __restrict__ o3, u16* __restrict__ o4, u16* __restrict__ o5,
    u16* __restrict__ o6, int nX, int nW)
{
  const int z = blockIdx.z;
  const float* in; u16* out; int n;
  switch (z){
    case 0: in=i0; out=o0; n=nX; break;
    case 1: in=i1; out=o1; n=nX; break;
    case 2: in=i2; out=o2; n=nX; break;
    case 3: in=i3; out=o3; n=nW; break;
    case 4: in=i4; out=o4; n=nW; break;
    case 5: in=i5; out=o5; n=nW; break;
    default: in=i6; out=o6; n=nW; break;
  }
  int idx = (blockIdx.x * blockDim.x + threadIdx.x) * 4;
  int stride = gridDim.x * blockDim.x * 4;
  for (int i = idx; i < n; i += stride){
    float4 v = *(const float4*)(in + i);
    u16x4 o = { f2bf(v.x), f2bf(v.y), f2bf(v.z), f2bf(v.w) };
    *(u16x4*)(out + i) = o;
  }
}

// ---------------- shared GEMM mainloop: acc = A[128 rows] x Bt[128 rows]^T ----------------
// 2-phase pipeline: stage(t+1) issued before compute(t); one barrier per K-step.
__device__ __forceinline__ void gemm_mainloop(
    const u16* __restrict__ A, const u16* __restrict__ Bt,
    int m0, int n0, u16* As, u16* Bs, f32x4 (&acc)[4][4])
{
  constexpr int K = E_DIM;
  constexpr int NT = K / 32;
  const int tid = threadIdx.x;
  const int lane = tid & 63;
  const int w = tid >> 6;
  const int wr = w >> 1, wc = w & 1;
  const int lr = lane & 15, lg = lane >> 4;

  #pragma unroll
  for (int i=0;i<4;i++)
    #pragma unroll
    for (int j=0;j<4;j++) acc[i][j] = (f32x4){0.f,0.f,0.f,0.f};

  auto STAGE = [&](int t, int b){
    int k0 = t * 32;
    #pragma unroll
    for (int r=0;r<2;++r){
      int c = r*256 + tid;
      int row = c >> 2, cc = (c & 3) * 8;
      load_lds16(A  + (size_t)(m0 + row)*K + k0 + cc,
                 (char*)As + b*8192 + (r*256 + w*64)*16);
      load_lds16(Bt + (size_t)(n0 + row)*K + k0 + cc,
                 (char*)Bs + b*8192 + (r*256 + w*64)*16);
    }
  };

  STAGE(0, 0);
  __syncthreads();
  for (int t = 0; t < NT; ++t){
    const int cur = t & 1;
    if (t + 1 < NT) STAGE(t+1, cur^1);
    bf16x8 af[4], bfr[4];
    #pragma unroll
    for (int i=0;i<4;i++){
      af[i]  = *(const bf16x8*)&As[cur*4096 + (wr*64 + i*16 + lr)*32 + lg*8];
      bfr[i] = *(const bf16x8*)&Bs[cur*4096 + (wc*64 + i*16 + lr)*32 + lg*8];
    }
    __builtin_amdgcn_s_setprio(1);
    #pragma unroll
    for (int i=0;i<4;i++)
      #pragma unroll
      for (int j=0;j<4;j++)
        acc[i][j] = __builtin_amdgcn_mfma_f32_16x16x32_bf16(af[i], bfr[j], acc[i][j], 0,0,0);
    __builtin_amdgcn_s_setprio(0);
    __syncthreads();
  }
}

struct QKVArgs {
  const u16* A[3]; const u16* Bw[3]; const float* bias[3];
  float scale[3]; u16* out[3];
};

// Q/K/V projections, one launch (blockIdx.z selects). Writes bf16 [B,H,L,D].
__global__ __launch_bounds__(256) void gemm_qkv(QKVArgs args){
  __shared__ __align__(16) u16 As[2*128*32];
  __shared__ __align__(16) u16 Bs[2*128*32];
  const int z = blockIdx.z;
  const int m0 = blockIdx.y * 128, n0 = blockIdx.x * 128;
  f32x4 acc[4][4];
  gemm_mainloop(args.A[z], args.Bw[z], m0, n0, As, Bs, acc);

  const int tid = threadIdx.x;
  const int lane = tid & 63;
  const int w = tid >> 6;
  const int wr = w >> 1, wc = w & 1;
  const int lr = lane & 15, lg = lane >> 4;
  const float* bias = args.bias[z];
  const float scale = args.scale[z];
  u16* outB = args.out[z];
  #pragma unroll
  for (int i=0;i<4;i++)
    #pragma unroll
    for (int j=0;j<4;j++)
      #pragma unroll
      for (int q=0;q<4;q++){
        int m = m0 + wr*64 + i*16 + lg*4 + q;
        int n = n0 + wc*64 + j*16 + lr;
        float v = (acc[i][j][q] + bias[n]) * scale;
        int t = m >> 2, b = m & 3;             // rows of [L,B,E]: m = t*B + b
        int h = n >> 6, d = n & 63;
        outB[ ((size_t)(b*H_N + h)*T_LEN + t)*D_H + d ] = f2bf(v);
      }
}

// Output projection: AO [B,T,E] -> d_out [T,B,E] fp32
__global__ __launch_bounds__(256) void gemm_out(
    const u16* __restrict__ A, const u16* __restrict__ Bt,
    const float* __restrict__ bias, float* __restrict__ outF)
{
  __shared__ __align__(16) u16 As[2*128*32];
  __shared__ __align__(16) u16 Bs[2*128*32];
  const int m0 = blockIdx.y * 128, n0 = blockIdx.x * 128;
  f32x4 acc[4][4];
  gemm_mainloop(A, Bt, m0, n0, As, Bs, acc);

  const int tid = threadIdx.x;
  const int lane = tid & 63;
  const int w = tid >> 6;
  const int wr = w >> 1, wc = w & 1;
  const int lr = lane & 15, lg = lane >> 4;
  #pragma unroll
  for (int i=0;i<4;i++)
    #pragma unroll
    for (int j=0;j<4;j++)
      #pragma unroll
      for (int q=0;q<4;q++){
        int m = m0 + wr*64 + i*16 + lg*4 + q;
        int n = n0 + wc*64 + j*16 + lr;
        float v = acc[i][j][q] + bias[n];
        int b = m >> 11, t = m & 2047;         // rows of AO [B,T,E]: m = b*T + t
        outF[ (size_t)(t*B_SZ + b)*E_DIM + n ] = v;
      }
}

// ---------------- V transpose: [B,H,S,D] -> [B,H,D,S] ----------------
__global__ __launch_bounds__(256) void transpose_v(const u16* __restrict__ Vb, u16* __restrict__ Vt){
  __shared__ u16 tile[64][65];
  int bh = blockIdx.y, s0 = blockIdx.x * 64;
  const u16* src = Vb + ((size_t)bh*T_LEN + s0)*D_H;
  u16* dst = Vt + (size_t)bh*D_H*T_LEN + s0;
  int tid = threadIdx.x;
  #pragma unroll
  for (int r=0;r<2;++r){
    int c = r*256 + tid;
    int s = c >> 3, d0 = (c & 7)*8;
    u16x8 v = *(const u16x8*)(src + (size_t)s*D_H + d0);
    #pragma unroll
    for (int j=0;j<8;j++) tile[d0+j][s] = v[j];
  }
  __syncthreads();
  #pragma unroll
  for (int r=0;r<2;++r){
    int c = r*256 + tid;
    int d = c >> 3, s1 = (c & 7)*8;
    u16x8 v;
    #pragma unroll
    for (int j=0;j<8;j++) v[j] = tile[d][s1+j];
    *(u16x8*)(dst + (size_t)d*T_LEN + s1) = v;
  }
}

// ---------------- causal flash attention (2-phase pipelined) ----------------
// Qb [B,H,T,D] (pre-scaled by 0.125*log2e), Kb [B,H,S,D], Vt [B,H,D,S] -> AO [B,T,E] bf16
__global__ __launch_bounds__(256) void attn_fwd(
    const u16* __restrict__ Qb, const u16* __restrict__ Kb,
    const u16* __restrict__ Vt, u16* __restrict__ AO)
{
  __shared__ __align__(16) u16 Ks[2*64*64];   // swizzled [s][d], double-buffered
  __shared__ __align__(16) u16 Vs[2*64*64];   // swizzled [d][s], double-buffered
  __shared__ __align__(16) u16 Ps[64*64];     // swizzled [q][s]
  const int tid = threadIdx.x;
  const int lane = tid & 63;
  const int wq = tid >> 6;
  const int lr = lane & 15, lg = lane >> 4;
  const int bh = blockIdx.y;
  const int qt = gridDim.x - 1 - blockIdx.x;  // reversed: heavy blocks dispatch first
  const int qb = qt * 64;
  const u16* Kbase = Kb + (size_t)bh * T_LEN * D_H;
  const u16* Vbase = Vt + (size_t)bh * D_H * T_LEN;

  bf16x8 qf[2];
  {
    const u16* qp = Qb + (size_t)bh*T_LEN*D_H + (size_t)(qb + wq*16 + lr)*D_H + lg*8;
    qf[0] = *(const bf16x8*)qp;
    qf[1] = *(const bf16x8*)(qp + 32);
  }

  auto STAGE = [&](int kt, int b){
    int s0 = kt * 64;
    #pragma unroll
    for (int r=0;r<2;++r){
      int c = r*256 + tid;
      int row = c >> 3;
      int colb = (c & 7) * 16;
      int scolb = colb ^ ((row & 7) << 4);
      load_lds16((const char*)(Kbase + (size_t)(s0 + row)*D_H) + scolb,
                 (char*)Ks + b*8192 + (r*256 + wq*64)*16);
      load_lds16((const char*)(Vbase + (size_t)row*T_LEN + s0) + scolb,
                 (char*)Vs + b*8192 + (r*256 + wq*64)*16);
    }
  };

  f32x4 o[4];
  #pragma unroll
  for (int f=0;f<4;f++) o[f] = (f32x4){0.f,0.f,0.f,0.f};
  float m_run = -INFINITY, l_run = 0.f;

  const int ntiles = qt + 1;
  STAGE(0, 0);
  __syncthreads();

  for (int kt = 0; kt < ntiles; ++kt){
    const int cur = kt & 1;
    if (kt + 1 < ntiles) STAGE(kt+1, cur^1);

    // S^T = K · Q^T : st[f][q] = S^T[s = f*16 + lg*4 + q][q_loc = wq*16 + lr]  (log2 units)
    f32x4 st[4];
    __builtin_amdgcn_s_setprio(1);
    #pragma unroll
    for (int f=0; f<4; ++f){
      st[f] = (f32x4){0.f,0.f,0.f,0.f};
      #pragma unroll
      for (int ks=0; ks<2; ++ks){
        int srow = f*16 + lr;
        int colb = (lg*16 + ks*64);
        int scolb = colb ^ ((lr & 7) << 4);   // (srow&7)==(lr&7)
        bf16x8 kf = *(const bf16x8*)((const char*)Ks + cur*8192 + srow*128 + scolb);
        st[f] = __builtin_amdgcn_mfma_f32_16x16x32_bf16(kf, qf[ks], st[f], 0,0,0);
      }
    }
    __builtin_amdgcn_s_setprio(0);

    // causal mask (diagonal tile only) + row max
    const bool diag = (kt == qt);
    float mx = -INFINITY;
    if (diag){
      #pragma unroll
      for (int f=0; f<4; ++f)
        #pragma unroll
        for (int q=0; q<4; ++q){
          int sl = f*16 + lg*4 + q;
          int ql = wq*16 + lr;
          float v = (sl > ql) ? -INFINITY : st[f][q];
          st[f][q] = v;
          mx = fmaxf(mx, v);
        }
    } else {
      #pragma unroll
      for (int f=0; f<4; ++f)
        #pragma unroll
        for (int q=0; q<4; ++q) mx = fmaxf(mx, st[f][q]);
    }
    mx = fmaxf(mx, __shfl_xor(mx, 16));
    mx = fmaxf(mx, __shfl_xor(mx, 32));

    // defer-max: skip O-rescale while running max is adequate (P bounded by 2^8)
    if (!__all(mx <= m_run + 8.0f)){
      float m_new = fmaxf(m_run, mx);
      float sc = fexp2(m_run - m_new);
      l_run *= sc;
      #pragma unroll
      for (int q=0; q<4; ++q){
        float fq = __shfl(sc, lg*4 + q);
        #pragma unroll
        for (int f=0; f<4; ++f) o[f][q] *= fq;
      }
      m_run = m_new;
    }

    float rsum = 0.f;
    #pragma unroll
    for (int f=0;f<4;++f)
      #pragma unroll
      for (int q=0;q<4;++q){
        float p = fexp2(st[f][q] - m_run);
        st[f][q] = p;
        rsum += p;
      }
    rsum += __shfl_xor(rsum, 16);
    rsum += __shfl_xor(rsum, 32);
    l_run += rsum;

    // P -> LDS (bf16), swizzled [q][s] stride 64; rows are per-wave private
    #pragma unroll
    for (int f=0;f<4;++f){
      u16x4 pk;
      #pragma unroll
      for (int q=0;q<4;++q) pk[q] = __builtin_bit_cast(u16, (__bf16)st[f][q]);
      int wb = (f*32 + lg*8) ^ ((lr & 7) << 4);
      *(u16x4*)((char*)Ps + (wq*16 + lr)*128 + wb) = pk;
    }

    // O += P · V
    __builtin_amdgcn_s_setprio(1);
    #pragma unroll
    for (int ks=0; ks<2; ++ks){
      int rb = (ks*64 + lg*16) ^ ((lr & 7) << 4);
      bf16x8 pf = *(const bf16x8*)((const char*)Ps + (wq*16 + lr)*128 + rb);
      #pragma unroll
      for (int f=0; f<4; ++f){
        int drow = f*16 + lr;
        int colb = (lg*16 + ks*64);
        int scolb = colb ^ ((lr & 7) << 4);
        bf16x8 vf = *(const bf16x8*)((const char*)Vs + cur*8192 + drow*128 + scolb);
        o[f] = __builtin_amdgcn_mfma_f32_16x16x32_bf16(pf, vf, o[f], 0,0,0);
      }
    }
    __builtin_amdgcn_s_setprio(0);
    __syncthreads();   // drains this iter's stage loads; guards both buffers
  }

  float linv[4];
  #pragma unroll
  for (int q=0;q<4;++q) linv[q] = 1.f / __shfl(l_run, lg*4 + q);
  const int b = bh >> 4, h = bh & 15;
  #pragma unroll
  for (int f=0;f<4;++f)
    #pragma unroll
    for (int q=0;q<4;++q){
      int qg = qb + wq*16 + lg*4 + q;
      int d = f*16 + lr;
      AO[ ((size_t)(b*T_LEN + qg))*E_DIM + h*D_H + d ] = f2bf(o[f][q] * linv[q]);
    }
}

extern "C" void kernel_launch(void* const* d_in, const int* in_sizes, int n_in,
                              void* d_out, int out_size, void* d_ws, size_t ws_size,
                              hipStream_t stream){
  const float* query = (const float*)d_in[0];
  const float* key   = (const float*)d_in[1];
  const float* value = (const float*)d_in[2];
  const float* Wq = (const float*)d_in[4];
  const float* bq = (const float*)d_in[5];
  const float* Wk = (const float*)d_in[6];
  const float* bk = (const float*)d_in[7];
  const float* Wv = (const float*)d_in[8];
  const float* bv = (const float*)d_in[9];
  const float* Wo = (const float*)d_in[10];
  const float* bo = (const float*)d_in[11];

  char* ws = (char*)d_ws;
  const size_t SZ_X = (size_t)M_ROWS * E_DIM * 2;   // 16 MB
  const size_t SZ_W = (size_t)E_DIM * E_DIM * 2;    // 2 MB
  u16* Xq  = (u16*)(ws);                    // reused as AO after Q-proj
  u16* Xk  = (u16*)(ws + SZ_X);             // reused as Vt after K-proj
  u16* Xv  = (u16*)(ws + 2*SZ_X);
  u16* Wqb = (u16*)(ws + 3*SZ_X);
  u16* Wkb = (u16*)(ws + 3*SZ_X + 1*SZ_W);
  u16* Wvb = (u16*)(ws + 3*SZ_X + 2*SZ_W);
  u16* Wob = (u16*)(ws + 3*SZ_X + 3*SZ_W);
  u16* Qb  = (u16*)(ws + 3*SZ_X + 4*SZ_W);
  u16* Kb  = (u16*)(ws + 4*SZ_X + 4*SZ_W);
  u16* Vb  = (u16*)(ws + 5*SZ_X + 4*SZ_W);
  u16* Vt  = Xk;
  u16* AO  = Xq;

  const int nX = M_ROWS * E_DIM;
  const int nW = E_DIM * E_DIM;
  cvt_all<<<dim3(1024,1,7), 256, 0, stream>>>(
      query, key, value, Wq, Wk, Wv, Wo,
      Xq, Xk, Xv, Wqb, Wkb, Wvb, Wob, nX, nW);

  const float QSCALE = 0.125f * 1.44269504f;   // 1/sqrt(D) * log2(e): scores in log2 domain
  QKVArgs qa;
  qa.A[0]=Xq;  qa.A[1]=Xk;  qa.A[2]=Xv;
  qa.Bw[0]=Wqb; qa.Bw[1]=Wkb; qa.Bw[2]=Wvb;
  qa.bias[0]=bq; qa.bias[1]=bk; qa.bias[2]=bv;
  qa.scale[0]=QSCALE; qa.scale[1]=1.0f; qa.scale[2]=1.0f;
  qa.out[0]=Qb; qa.out[1]=Kb; qa.out[2]=Vb;
  gemm_qkv<<<dim3(E_DIM/128, M_ROWS/128, 3), 256, 0, stream>>>(qa);
  transpose_v<<<dim3(T_LEN/64, B_SZ*H_N), 256, 0, stream>>>(Vb, Vt);
  attn_fwd<<<dim3(T_LEN/64, B_SZ*H_N), 256, 0, stream>>>(Qb, Kb, Vt, AO);
  gemm_out<<<dim3(E_DIM/128, M_ROWS/128), 256, 0, stream>>>(AO, Wob, bo, (float*)d_out);
}

// Round 7
// 253.488 us; speedup vs baseline: 1.1937x; 1.0403x over previous
//
#include <hip/hip_runtime.h>

typedef unsigned short u16;
typedef __attribute__((ext_vector_type(8))) __bf16 bf16x8;
typedef __attribute__((ext_vector_type(4))) float f32x4;
typedef __attribute__((ext_vector_type(16))) float f32x16;
typedef __attribute__((ext_vector_type(4))) unsigned short u16x4;
typedef __attribute__((ext_vector_type(8))) unsigned short u16x8;
typedef __attribute__((ext_vector_type(4))) unsigned int u32x4;

#define T_LEN 2048
#define B_SZ 4
#define E_DIM 1024
#define H_N 16
#define D_H 64
#define M_ROWS (T_LEN * B_SZ)   // 8192

__device__ __forceinline__ u16 f2bf(float f){
  unsigned u = __builtin_bit_cast(unsigned, f);
  u += 0x7fffu + ((u >> 16) & 1u);
  return (u16)(u >> 16);
}

__device__ __forceinline__ float fexp2(float x){
#if __has_builtin(__builtin_amdgcn_exp2f)
  return __builtin_amdgcn_exp2f(x);
#else
  return exp2f(x);
#endif
}

__device__ __forceinline__ unsigned cvtpk(float lo, float hi){
  unsigned w;
  asm("v_cvt_pk_bf16_f32 %0, %1, %2" : "=v"(w) : "v"(lo), "v"(hi));
  return w;
}
// cross-half (lane ^ 32) combine — __shfl_xor uses distinct SSA values,
// immune to the permlane32_swap self-aliasing hazard (R5/R6 bug).
__device__ __forceinline__ float xhalf_max(float x){
  return fmaxf(x, __shfl_xor(x, 32));
}
__device__ __forceinline__ float xhalf_sum(float x){
  return x + __shfl_xor(x, 32);
}

__device__ __forceinline__ void load_lds16(const void* g, void* l){
  __builtin_amdgcn_global_load_lds(
      (const __attribute__((address_space(1))) void*)g,
      (__attribute__((address_space(3))) void*)l, 16, 0, 0);
}

// ---------------- fp32 -> bf16 convert, all 7 tensors in one launch ----------------
__global__ void cvt_all(
    const float* __restrict__ i0, const float* __restrict__ i1, const float* __restrict__ i2,
    const float* __restrict__ i3, const float* __restrict__ i4, const float* __restrict__ i5,
    const float* __restrict__ i6,
    u16* __restrict__ o0, u16* __restrict__ o1, u16* __restrict__ o2,
    u16* __restrict__ o3, u16* __restrict__ o4, u16* __restrict__ o5,
    u16* __restrict__ o6, int nX, int nW)
{
  const int z = blockIdx.z;
  const float* in; u16* out; int n;
  switch (z){
    case 0: in=i0; out=o0; n=nX; break;
    case 1: in=i1; out=o1; n=nX; break;
    case 2: in=i2; out=o2; n=nX; break;
    case 3: in=i3; out=o3; n=nW; break;
    case 4: in=i4; out=o4; n=nW; break;
    case 5: in=i5; out=o5; n=nW; break;
    default: in=i6; out=o6; n=nW; break;
  }
  int idx = (blockIdx.x * blockDim.x + threadIdx.x) * 4;
  int stride = gridDim.x * blockDim.x * 4;
  for (int i = idx; i < n; i += stride){
    float4 v = *(const float4*)(in + i);
    u16x4 o = { f2bf(v.x), f2bf(v.y), f2bf(v.z), f2bf(v.w) };
    *(u16x4*)(out + i) = o;
  }
}

// ---------------- shared GEMM mainloop (2-phase pipelined, 128x128 tile) ----------------
__device__ __forceinline__ void gemm_mainloop(
    const u16* __restrict__ A, const u16* __restrict__ Bt,
    int m0, int n0, u16* As, u16* Bs, f32x4 (&acc)[4][4])
{
  constexpr int K = E_DIM;
  constexpr int NT = K / 32;
  const int tid = threadIdx.x;
  const int lane = tid & 63;
  const int w = tid >> 6;
  const int wr = w >> 1, wc = w & 1;
  const int lr = lane & 15, lg = lane >> 4;

  #pragma unroll
  for (int i=0;i<4;i++)
    #pragma unroll
    for (int j=0;j<4;j++) acc[i][j] = (f32x4){0.f,0.f,0.f,0.f};

  auto STAGE = [&](int t, int b){
    int k0 = t * 32;
    #pragma unroll
    for (int r=0;r<2;++r){
      int c = r*256 + tid;
      int row = c >> 2, cc = (c & 3) * 8;
      load_lds16(A  + (size_t)(m0 + row)*K + k0 + cc,
                 (char*)As + b*8192 + (r*256 + w*64)*16);
      load_lds16(Bt + (size_t)(n0 + row)*K + k0 + cc,
                 (char*)Bs + b*8192 + (r*256 + w*64)*16);
    }
  };

  STAGE(0, 0);
  __syncthreads();
  for (int t = 0; t < NT; ++t){
    const int cur = t & 1;
    if (t + 1 < NT) STAGE(t+1, cur^1);
    bf16x8 af[4], bfr[4];
    #pragma unroll
    for (int i=0;i<4;i++){
      af[i]  = *(const bf16x8*)&As[cur*4096 + (wr*64 + i*16 + lr)*32 + lg*8];
      bfr[i] = *(const bf16x8*)&Bs[cur*4096 + (wc*64 + i*16 + lr)*32 + lg*8];
    }
    #pragma unroll
    for (int i=0;i<4;i++)
      #pragma unroll
      for (int j=0;j<4;j++)
        acc[i][j] = __builtin_amdgcn_mfma_f32_16x16x32_bf16(af[i], bfr[j], acc[i][j], 0,0,0);
    __syncthreads();
  }
}

struct QKVArgs {
  const u16* A[3]; const u16* Bw[3]; const float* bias[3];
  float scale[3]; u16* out[3];
};

// Q/K/V projections, one launch (blockIdx.z selects). Writes bf16 [B,H,L,D].
__global__ __launch_bounds__(256) void gemm_qkv(QKVArgs args){
  __shared__ __align__(16) u16 As[2*128*32];
  __shared__ __align__(16) u16 Bs[2*128*32];
  const int z = blockIdx.z;
  const int m0 = blockIdx.y * 128, n0 = blockIdx.x * 128;
  f32x4 acc[4][4];
  gemm_mainloop(args.A[z], args.Bw[z], m0, n0, As, Bs, acc);

  const int tid = threadIdx.x;
  const int lane = tid & 63;
  const int w = tid >> 6;
  const int wr = w >> 1, wc = w & 1;
  const int lr = lane & 15, lg = lane >> 4;
  const float* bias = args.bias[z];
  const float scale = args.scale[z];
  u16* outB = args.out[z];
  #pragma unroll
  for (int i=0;i<4;i++)
    #pragma unroll
    for (int j=0;j<4;j++)
      #pragma unroll
      for (int q=0;q<4;q++){
        int m = m0 + wr*64 + i*16 + lg*4 + q;
        int n = n0 + wc*64 + j*16 + lr;
        float v = (acc[i][j][q] + bias[n]) * scale;
        int t = m >> 2, b = m & 3;             // rows of [L,B,E]: m = t*B + b
        int h = n >> 6, d = n & 63;
        outB[ ((size_t)(b*H_N + h)*T_LEN + t)*D_H + d ] = f2bf(v);
      }
}

// Output projection: AO [B,T,E] -> d_out [T,B,E] fp32
__global__ __launch_bounds__(256) void gemm_out(
    const u16* __restrict__ A, const u16* __restrict__ Bt,
    const float* __restrict__ bias, float* __restrict__ outF)
{
  __shared__ __align__(16) u16 As[2*128*32];
  __shared__ __align__(16) u16 Bs[2*128*32];
  const int m0 = blockIdx.y * 128, n0 = blockIdx.x * 128;
  f32x4 acc[4][4];
  gemm_mainloop(A, Bt, m0, n0, As, Bs, acc);

  const int tid = threadIdx.x;
  const int lane = tid & 63;
  const int w = tid >> 6;
  const int wr = w >> 1, wc = w & 1;
  const int lr = lane & 15, lg = lane >> 4;
  #pragma unroll
  for (int i=0;i<4;i++)
    #pragma unroll
    for (int j=0;j<4;j++)
      #pragma unroll
      for (int q=0;q<4;q++){
        int m = m0 + wr*64 + i*16 + lg*4 + q;
        int n = n0 + wc*64 + j*16 + lr;
        float v = acc[i][j][q] + bias[n];
        int b = m >> 11, t = m & 2047;         // rows of AO [B,T,E]: m = b*T + t
        outF[ (size_t)(t*B_SZ + b)*E_DIM + n ] = v;
      }
}

// ---------------- V transpose: [B,H,S,D] -> [B,H,D,S], s quad-permuted ----------------
// Position p holds s = perm(p), perm = swap quads [4-7]<->[8-11] within each 16.
// This makes V's (lane-half, elem)->s map IDENTICAL to P's 32x32 C-layout
// residency, so the PV MFMA pairs them correctly for ANY hardware k-slot order.
__global__ __launch_bounds__(256) void transpose_v(const u16* __restrict__ Vb, u16* __restrict__ Vt){
  __shared__ u16 tile[64][65];
  int bh = blockIdx.y, s0 = blockIdx.x * 64;
  const u16* src = Vb + ((size_t)bh*T_LEN + s0)*D_H;
  u16* dst = Vt + (size_t)bh*D_H*T_LEN + s0;
  int tid = threadIdx.x;
  #pragma unroll
  for (int r=0;r<2;++r){
    int c = r*256 + tid;
    int s = c >> 3, d0 = (c & 7)*8;
    u16x8 v = *(const u16x8*)(src + (size_t)s*D_H + d0);
    #pragma unroll
    for (int j=0;j<8;j++) tile[d0+j][s] = v[j];
  }
  __syncthreads();
  #pragma unroll
  for (int r=0;r<2;++r){
    int c = r*256 + tid;
    int d = c >> 3, s1 = (c & 7)*8;
    u16x8 v;
    #pragma unroll
    for (int j=0;j<8;j++){
      int p = s1 + j;
      int sp = (p & ~12) | ((p & 4) << 1) | ((p & 8) >> 1);   // involution
      v[j] = tile[d][sp];
    }
    *(u16x8*)(dst + (size_t)d*T_LEN + s1) = v;
  }
}

// ---------------- causal flash attention, 32x32 MFMA, QBLK=128, KVBLK=64 ----------------
// Qb [B,H,T,D] (pre-scaled by 0.125*log2e), Kb [B,H,S,D], Vt [B,H,D,S(perm)] -> AO [B,T,E]
// S^T = K·Q^T in 32x32 C-layout: q = lane&31 (lane-local softmax stats),
// s = (reg&3)+8*(reg>>2)+4*(lane>>5) (+32*subtile). P feeds PV directly from registers.
__global__ __launch_bounds__(256) void attn_fwd(
    const u16* __restrict__ Qb, const u16* __restrict__ Kb,
    const u16* __restrict__ Vt, u16* __restrict__ AO)
{
  __shared__ __align__(16) u16 smem[4*64*64];   // Ks dbuf [0,16K)B, Vs dbuf [16K,32K)B
  u16* Ks = smem;
  u16* Vs = smem + 2*64*64;
  const int tid = threadIdx.x;
  const int lane = tid & 63;
  const int wq = tid >> 6;          // wave's q sub-block (32 rows each)
  const int l31 = lane & 31;
  const int hi = lane >> 5;
  const int bh = blockIdx.y;
  const int qt = gridDim.x - 1 - blockIdx.x;   // reversed: heavy blocks first
  const int qb = qt * 128;
  const u16* Kbase = Kb + (size_t)bh * T_LEN * D_H;
  const u16* Vbase = Vt + (size_t)bh * D_H * T_LEN;
  const int qg = qb + wq*32 + l31;

  // Q B-fragments for 4 K-steps: col=q=l31, k = kk*16 + hi*8 + e
  bf16x8 qf[4];
  {
    const u16* qp = Qb + (size_t)bh*T_LEN*D_H + (size_t)qg*D_H + hi*8;
    #pragma unroll
    for (int kk=0;kk<4;++kk) qf[kk] = *(const bf16x8*)(qp + kk*16);
  }

  auto STAGE = [&](int j, int b){
    int s0 = j * 64;
    #pragma unroll
    for (int r=0;r<2;++r){
      int c = r*256 + tid;
      int row = c >> 3;
      int colb = (c & 7) * 16;
      int scolb = colb ^ ((row & 7) << 4);
      load_lds16((const char*)(Kbase + (size_t)(s0 + row)*D_H) + scolb,
                 (char*)Ks + b*8192 + (r*256 + wq*64)*16);
      load_lds16((const char*)(Vbase + (size_t)row*T_LEN + s0) + scolb,
                 (char*)Vs + b*8192 + (r*256 + wq*64)*16);
    }
  };

  f32x16 o[2];
  #pragma unroll
  for (int f=0;f<2;++f)
    #pragma unroll
    for (int r=0;r<16;++r) o[f][r] = 0.f;
  float m_run = -INFINITY, l_run = 0.f;

  const int ntiles = 2*qt + 2;
  STAGE(0, 0);
  __syncthreads();

  for (int j = 0; j < ntiles; ++j){
    const int cur = j & 1;
    if (j + 1 < ntiles) STAGE(j+1, cur^1);
    const char* Kc = (const char*)Ks + cur*8192;
    const char* Vc = (const char*)Vs + cur*8192;

    // last tile: waves 0,1 (q rows qb..qb+63) are fully masked -> skip
    const bool fullmask = (j == 2*qt + 1) && (wq < 2);
    if (!fullmask){
      // ---- QK^T ----
      f32x16 st[2];
      #pragma unroll
      for (int i=0;i<2;++i)
        #pragma unroll
        for (int r=0;r<16;++r) st[i][r] = 0.f;
      __builtin_amdgcn_s_setprio(1);
      #pragma unroll
      for (int i=0;i<2;++i){
        #pragma unroll
        for (int kk=0;kk<4;++kk){
          int row = i*32 + l31;
          int colb = (kk*32 + hi*16) ^ ((row & 7) << 4);
          bf16x8 kf = *(const bf16x8*)(Kc + row*128 + colb);
          st[i] = __builtin_amdgcn_mfma_f32_32x32x16_bf16(kf, qf[kk], st[i], 0,0,0);
        }
      }
      __builtin_amdgcn_s_setprio(0);

      // ---- mask + row max (lane-local q) ----
      const int s0 = j*64;
      float mx = -INFINITY;
      if (j >= 2*qt){
        #pragma unroll
        for (int i=0;i<2;++i)
          #pragma unroll
          for (int r=0;r<16;++r){
            int sg = s0 + i*32 + (r&3) + 8*(r>>2) + 4*hi;
            float v = (sg > qg) ? -INFINITY : st[i][r];
            st[i][r] = v;
            mx = fmaxf(mx, v);
          }
      } else {
        #pragma unroll
        for (int i=0;i<2;++i)
          #pragma unroll
          for (int r=0;r<16;++r) mx = fmaxf(mx, st[i][r]);
      }
      mx = xhalf_max(mx);

      // defer-max: rescale only when needed (P bounded by 2^8)
      if (!__all(mx <= m_run + 8.0f)){
        float m_new = fmaxf(m_run, mx);
        float sc = fexp2(m_run - m_new);
        l_run *= sc;
        #pragma unroll
        for (int f=0;f<2;++f)
          #pragma unroll
          for (int r=0;r<16;++r) o[f][r] *= sc;
        m_run = m_new;
      }

      // ---- exp + row sum ----
      float rsum = 0.f;
      #pragma unroll
      for (int i=0;i<2;++i)
        #pragma unroll
        for (int r=0;r<16;++r){
          float p = fexp2(st[i][r] - m_run);
          st[i][r] = p;
          rsum += p;
        }
      l_run += xhalf_sum(rsum);

      // ---- pack P into PV B-fragments: DIRECT (V s-order quad-permuted to match) ----
      u32x4 Bfr[4];
      #pragma unroll
      for (int i=0;i<2;++i){
        Bfr[2*i]   = (u32x4){ cvtpk(st[i][0],  st[i][1]),  cvtpk(st[i][2],  st[i][3]),
                              cvtpk(st[i][4],  st[i][5]),  cvtpk(st[i][6],  st[i][7]) };
        Bfr[2*i+1] = (u32x4){ cvtpk(st[i][8],  st[i][9]),  cvtpk(st[i][10], st[i][11]),
                              cvtpk(st[i][12], st[i][13]), cvtpk(st[i][14], st[i][15]) };
      }

      // ---- O^T += V^T · P^T ----
      __builtin_amdgcn_s_setprio(1);
      #pragma unroll
      for (int ss=0; ss<4; ++ss){
        bf16x8 pb = __builtin_bit_cast(bf16x8, Bfr[ss]);
        #pragma unroll
        for (int f=0; f<2; ++f){
          int row = f*32 + l31;
          int colb = (ss*32 + hi*16) ^ ((row & 7) << 4);
          bf16x8 vf = *(const bf16x8*)(Vc + row*128 + colb);
          o[f] = __builtin_amdgcn_mfma_f32_32x32x16_bf16(vf, pb, o[f], 0,0,0);
        }
      }
      __builtin_amdgcn_s_setprio(0);
    }
    __syncthreads();   // staging for j+1 complete; both buffers safe
  }

  // ---- epilogue: normalize, transpose via LDS, coalesced store ----
  float linv = 1.f / l_run;
  {
    char* Osh = (char*)smem;           // reuse; per-wave region stride 136B x 32 rows
    unsigned base = wq*4352;
    #pragma unroll
    for (int f=0;f<2;++f)
      #pragma unroll
      for (int m=0;m<8;++m){
        unsigned word = cvtpk(o[f][2*m]*linv, o[f][2*m+1]*linv);
        int d0 = (m&1)*2 + 8*(m>>1) + 4*hi + 32*f;
        *(unsigned*)(Osh + base + l31*136 + d0*2) = word;
      }
  }
  __syncthreads();
  {
    const int b_ = bh >> 4, h = bh & 15;
    int q = tid >> 1, half = tid & 1;    // q 0..127, 64B per thread
    const char* src = (const char*)smem + (q>>5)*4352 + (q&31)*136 + half*64;
    u16* dst = AO + ((size_t)(b_*T_LEN + qb + q))*E_DIM + h*D_H + half*32;
    #pragma unroll
    for (int k=0;k<4;++k)
      *(u16x8*)(dst + k*8) = *(const u16x8*)(src + k*16);
  }
}

extern "C" void kernel_launch(void* const* d_in, const int* in_sizes, int n_in,
                              void* d_out, int out_size, void* d_ws, size_t ws_size,
                              hipStream_t stream){
  const float* query = (const float*)d_in[0];
  const float* key   = (const float*)d_in[1];
  const float* value = (const float*)d_in[2];
  const float* Wq = (const float*)d_in[4];
  const float* bq = (const float*)d_in[5];
  const float* Wk = (const float*)d_in[6];
  const float* bk = (const float*)d_in[7];
  const float* Wv = (const float*)d_in[8];
  const float* bv = (const float*)d_in[9];
  const float* Wo = (const float*)d_in[10];
  const float* bo = (const float*)d_in[11];

  char* ws = (char*)d_ws;
  const size_t SZ_X = (size_t)M_ROWS * E_DIM * 2;   // 16 MB
  const size_t SZ_W = (size_t)E_DIM * E_DIM * 2;    // 2 MB
  u16* Xq  = (u16*)(ws);                    // reused as AO after Q-proj
  u16* Xk  = (u16*)(ws + SZ_X);             // reused as Vt after K-proj
  u16* Xv  = (u16*)(ws + 2*SZ_X);
  u16* Wqb = (u16*)(ws + 3*SZ_X);
  u16* Wkb = (u16*)(ws + 3*SZ_X + 1*SZ_W);
  u16* Wvb = (u16*)(ws + 3*SZ_X + 2*SZ_W);
  u16* Wob = (u16*)(ws + 3*SZ_X + 3*SZ_W);
  u16* Qb  = (u16*)(ws + 3*SZ_X + 4*SZ_W);
  u16* Kb  = (u16*)(ws + 4*SZ_X + 4*SZ_W);
  u16* Vb  = (u16*)(ws + 5*SZ_X + 4*SZ_W);
  u16* Vt  = Xk;
  u16* AO  = Xq;

  const int nX = M_ROWS * E_DIM;
  const int nW = E_DIM * E_DIM;
  cvt_all<<<dim3(1024,1,7), 256, 0, stream>>>(
      query, key, value, Wq, Wk, Wv, Wo,
      Xq, Xk, Xv, Wqb, Wkb, Wvb, Wob, nX, nW);

  const float QSCALE = 0.125f * 1.44269504f;   // 1/sqrt(D) * log2(e): scores in log2 domain
  QKVArgs qa;
  qa.A[0]=Xq;  qa.A[1]=Xk;  qa.A[2]=Xv;
  qa.Bw[0]=Wqb; qa.Bw[1]=Wkb; qa.Bw[2]=Wvb;
  qa.bias[0]=bq; qa.bias[1]=bk; qa.bias[2]=bv;
  qa.scale[0]=QSCALE; qa.scale[1]=1.0f; qa.scale[2]=1.0f;
  qa.out[0]=Qb; qa.out[1]=Kb; qa.out[2]=Vb;
  gemm_qkv<<<dim3(E_DIM/128, M_ROWS/128, 3), 256, 0, stream>>>(qa);
  transpose_v<<<dim3(T_LEN/64, B_SZ*H_N), 256, 0, stream>>>(Vb, Vt);
  attn_fwd<<<dim3(T_LEN/128, B_SZ*H_N), 256, 0, stream>>>(Qb, Kb, Vt, AO);
  gemm_out<<<dim3(E_DIM/128, M_ROWS/128), 256, 0, stream>>>(AO, Wob, bo, (float*)d_out);
}

// Round 8
// 210.818 us; speedup vs baseline: 1.4353x; 1.2024x over previous
//
#include <hip/hip_runtime.h>

typedef unsigned short u16;
typedef __attribute__((ext_vector_type(8))) __bf16 bf16x8;
typedef __attribute__((ext_vector_type(4))) float f32x4;
typedef __attribute__((ext_vector_type(16))) float f32x16;
typedef __attribute__((ext_vector_type(4))) unsigned short u16x4;
typedef __attribute__((ext_vector_type(8))) unsigned short u16x8;
typedef __attribute__((ext_vector_type(4))) unsigned int u32x4;

#define T_LEN 2048
#define B_SZ 4
#define E_DIM 1024
#define H_N 16
#define D_H 64
#define M_ROWS (T_LEN * B_SZ)   // 8192
#define NQT (T_LEN / 128)       // 16 q-tiles

__device__ __forceinline__ u16 f2bf(float f){
  unsigned u = __builtin_bit_cast(unsigned, f);
  u += 0x7fffu + ((u >> 16) & 1u);
  return (u16)(u >> 16);
}

__device__ __forceinline__ float fexp2(float x){
#if __has_builtin(__builtin_amdgcn_exp2f)
  return __builtin_amdgcn_exp2f(x);
#else
  return exp2f(x);
#endif
}

__device__ __forceinline__ unsigned cvtpk(float lo, float hi){
  unsigned w;
  asm("v_cvt_pk_bf16_f32 %0, %1, %2" : "=v"(w) : "v"(lo), "v"(hi));
  return w;
}
// cross-half (lane ^ 32) combine — distinct SSA values, no aliasing hazard
__device__ __forceinline__ float xhalf_max(float x){
  return fmaxf(x, __shfl_xor(x, 32));
}
__device__ __forceinline__ float xhalf_sum(float x){
  return x + __shfl_xor(x, 32);
}

__device__ __forceinline__ void load_lds16(const void* g, void* l){
  __builtin_amdgcn_global_load_lds(
      (const __attribute__((address_space(1))) void*)g,
      (__attribute__((address_space(3))) void*)l, 16, 0, 0);
}

// ---------------- fp32 -> bf16 convert, all 7 tensors in one launch ----------------
__global__ void cvt_all(
    const float* __restrict__ i0, const float* __restrict__ i1, const float* __restrict__ i2,
    const float* __restrict__ i3, const float* __restrict__ i4, const float* __restrict__ i5,
    const float* __restrict__ i6,
    u16* __restrict__ o0, u16* __restrict__ o1, u16* __restrict__ o2,
    u16* __restrict__ o3, u16* __restrict__ o4, u16* __restrict__ o5,
    u16* __restrict__ o6, int nX, int nW)
{
  const int z = blockIdx.z;
  const float* in; u16* out; int n;
  switch (z){
    case 0: in=i0; out=o0; n=nX; break;
    case 1: in=i1; out=o1; n=nX; break;
    case 2: in=i2; out=o2; n=nX; break;
    case 3: in=i3; out=o3; n=nW; break;
    case 4: in=i4; out=o4; n=nW; break;
    case 5: in=i5; out=o5; n=nW; break;
    default: in=i6; out=o6; n=nW; break;
  }
  int idx = (blockIdx.x * blockDim.x + threadIdx.x) * 4;
  int stride = gridDim.x * blockDim.x * 4;
  for (int i = idx; i < n; i += stride){
    float4 v = *(const float4*)(in + i);
    u16x4 o = { f2bf(v.x), f2bf(v.y), f2bf(v.z), f2bf(v.w) };
    *(u16x4*)(out + i) = o;
  }
}

// ---------------- shared GEMM mainloop (2-phase pipelined, 128x128 tile) ----------------
__device__ __forceinline__ void gemm_mainloop(
    const u16* __restrict__ A, const u16* __restrict__ Bt,
    int m0, int n0, u16* As, u16* Bs, f32x4 (&acc)[4][4])
{
  constexpr int K = E_DIM;
  constexpr int NT = K / 32;
  const int tid = threadIdx.x;
  const int lane = tid & 63;
  const int w = tid >> 6;
  const int wr = w >> 1, wc = w & 1;
  const int lr = lane & 15, lg = lane >> 4;

  #pragma unroll
  for (int i=0;i<4;i++)
    #pragma unroll
    for (int j=0;j<4;j++) acc[i][j] = (f32x4){0.f,0.f,0.f,0.f};

  auto STAGE = [&](int t, int b){
    int k0 = t * 32;
    #pragma unroll
    for (int r=0;r<2;++r){
      int c = r*256 + tid;
      int row = c >> 2, cc = (c & 3) * 8;
      load_lds16(A  + (size_t)(m0 + row)*K + k0 + cc,
                 (char*)As + b*8192 + (r*256 + w*64)*16);
      load_lds16(Bt + (size_t)(n0 + row)*K + k0 + cc,
                 (char*)Bs + b*8192 + (r*256 + w*64)*16);
    }
  };

  STAGE(0, 0);
  __syncthreads();
  for (int t = 0; t < NT; ++t){
    const int cur = t & 1;
    if (t + 1 < NT) STAGE(t+1, cur^1);
    bf16x8 af[4], bfr[4];
    #pragma unroll
    for (int i=0;i<4;i++){
      af[i]  = *(const bf16x8*)&As[cur*4096 + (wr*64 + i*16 + lr)*32 + lg*8];
      bfr[i] = *(const bf16x8*)&Bs[cur*4096 + (wc*64 + i*16 + lr)*32 + lg*8];
    }
    #pragma unroll
    for (int i=0;i<4;i++)
      #pragma unroll
      for (int j=0;j<4;j++)
        acc[i][j] = __builtin_amdgcn_mfma_f32_16x16x32_bf16(af[i], bfr[j], acc[i][j], 0,0,0);
    __syncthreads();
  }
}

struct QKVArgs {
  const u16* A[3]; const u16* Bw[3]; const float* bias[3];
  float scale[3]; u16* out[3];
};

// Q/K/V projections, one launch (blockIdx.z selects). Writes bf16 [B,H,L,D].
__global__ __launch_bounds__(256) void gemm_qkv(QKVArgs args){
  __shared__ __align__(16) u16 As[2*128*32];
  __shared__ __align__(16) u16 Bs[2*128*32];
  const int z = blockIdx.z;
  const int m0 = blockIdx.y * 128, n0 = blockIdx.x * 128;
  f32x4 acc[4][4];
  gemm_mainloop(args.A[z], args.Bw[z], m0, n0, As, Bs, acc);

  const int tid = threadIdx.x;
  const int lane = tid & 63;
  const int w = tid >> 6;
  const int wr = w >> 1, wc = w & 1;
  const int lr = lane & 15, lg = lane >> 4;
  const float* bias = args.bias[z];
  const float scale = args.scale[z];
  u16* outB = args.out[z];
  #pragma unroll
  for (int i=0;i<4;i++)
    #pragma unroll
    for (int j=0;j<4;j++)
      #pragma unroll
      for (int q=0;q<4;q++){
        int m = m0 + wr*64 + i*16 + lg*4 + q;
        int n = n0 + wc*64 + j*16 + lr;
        float v = (acc[i][j][q] + bias[n]) * scale;
        int t = m >> 2, b = m & 3;             // rows of [L,B,E]: m = t*B + b
        int h = n >> 6, d = n & 63;
        outB[ ((size_t)(b*H_N + h)*T_LEN + t)*D_H + d ] = f2bf(v);
      }
}

// Output projection: AO [B,T,E] -> d_out [T,B,E] fp32
__global__ __launch_bounds__(256) void gemm_out(
    const u16* __restrict__ A, const u16* __restrict__ Bt,
    const float* __restrict__ bias, float* __restrict__ outF)
{
  __shared__ __align__(16) u16 As[2*128*32];
  __shared__ __align__(16) u16 Bs[2*128*32];
  const int m0 = blockIdx.y * 128, n0 = blockIdx.x * 128;
  f32x4 acc[4][4];
  gemm_mainloop(A, Bt, m0, n0, As, Bs, acc);

  const int tid = threadIdx.x;
  const int lane = tid & 63;
  const int w = tid >> 6;
  const int wr = w >> 1, wc = w & 1;
  const int lr = lane & 15, lg = lane >> 4;
  #pragma unroll
  for (int i=0;i<4;i++)
    #pragma unroll
    for (int j=0;j<4;j++)
      #pragma unroll
      for (int q=0;q<4;q++){
        int m = m0 + wr*64 + i*16 + lg*4 + q;
        int n = n0 + wc*64 + j*16 + lr;
        float v = acc[i][j][q] + bias[n];
        int b = m >> 11, t = m & 2047;         // rows of AO [B,T,E]: m = b*T + t
        outF[ (size_t)(t*B_SZ + b)*E_DIM + n ] = v;
      }
}

// ---------------- V transpose: [B,H,S,D] -> [B,H,D,S], s quad-permuted ----------------
// Position p holds s = perm(p), perm = swap quads [4-7]<->[8-11] within each 16.
__global__ __launch_bounds__(256) void transpose_v(const u16* __restrict__ Vb, u16* __restrict__ Vt){
  __shared__ u16 tile[64][65];
  int bh = blockIdx.y, s0 = blockIdx.x * 64;
  const u16* src = Vb + ((size_t)bh*T_LEN + s0)*D_H;
  u16* dst = Vt + (size_t)bh*D_H*T_LEN + s0;
  int tid = threadIdx.x;
  #pragma unroll
  for (int r=0;r<2;++r){
    int c = r*256 + tid;
    int s = c >> 3, d0 = (c & 7)*8;
    u16x8 v = *(const u16x8*)(src + (size_t)s*D_H + d0);
    #pragma unroll
    for (int j=0;j<8;j++) tile[d0+j][s] = v[j];
  }
  __syncthreads();
  #pragma unroll
  for (int r=0;r<2;++r){
    int c = r*256 + tid;
    int d = c >> 3, s1 = (c & 7)*8;
    u16x8 v;
    #pragma unroll
    for (int j=0;j<8;j++){
      int p = s1 + j;
      int sp = (p & ~12) | ((p & 4) << 1) | ((p & 8) >> 1);   // involution
      v[j] = tile[d][sp];
    }
    *(u16x8*)(dst + (size_t)d*T_LEN + s1) = v;
  }
}

// ---------------- causal flash attention, 32x32 MFMA, QBLK=128, KVBLK=64 ----------------
// Each block processes TWO q-tiles: qt = NQT-1-x (heavy, first) and qt = x (light).
// Constant work per block: (2(NQT-1-x)+2)+(2x+2) = 2*NQT+2 tiles -> no CU-level tail.
__global__ __launch_bounds__(256) void attn_fwd(
    const u16* __restrict__ Qb, const u16* __restrict__ Kb,
    const u16* __restrict__ Vt, u16* __restrict__ AO)
{
  __shared__ __align__(16) u16 smem[4*64*64];   // Ks dbuf [0,16K)B, Vs dbuf [16K,32K)B
  u16* Ks = smem;
  u16* Vs = smem + 2*64*64;
  const int tid = threadIdx.x;
  const int lane = tid & 63;
  const int wq = tid >> 6;          // wave's q sub-block (32 rows each)
  const int l31 = lane & 31;
  const int hi = lane >> 5;
  const int bh = blockIdx.y;
  const u16* Kbase = Kb + (size_t)bh * T_LEN * D_H;
  const u16* Vbase = Vt + (size_t)bh * D_H * T_LEN;
  const int b_ = bh >> 4, h = bh & 15;

  auto STAGE = [&](int j, int b){
    int s0 = j * 64;
    #pragma unroll
    for (int r=0;r<2;++r){
      int c = r*256 + tid;
      int row = c >> 3;
      int colb = (c & 7) * 16;
      int scolb = colb ^ ((row & 7) << 4);
      load_lds16((const char*)(Kbase + (size_t)(s0 + row)*D_H) + scolb,
                 (char*)Ks + b*8192 + (r*256 + wq*64)*16);
      load_lds16((const char*)(Vbase + (size_t)row*T_LEN + s0) + scolb,
                 (char*)Vs + b*8192 + (r*256 + wq*64)*16);
    }
  };

  #pragma unroll 1
  for (int ph = 0; ph < 2; ++ph){
    const int qt = ph ? blockIdx.x : (NQT - 1 - blockIdx.x);
    const int qb = qt * 128;
    const int qg = qb + wq*32 + l31;

    // Q B-fragments: col=q=l31, k = kk*16 + hi*8 + e
    bf16x8 qf[4];
    {
      const u16* qp = Qb + (size_t)bh*T_LEN*D_H + (size_t)qg*D_H + hi*8;
      #pragma unroll
      for (int kk=0;kk<4;++kk) qf[kk] = *(const bf16x8*)(qp + kk*16);
    }

    f32x16 o[2];
    #pragma unroll
    for (int f=0;f<2;++f)
      #pragma unroll
      for (int r=0;r<16;++r) o[f][r] = 0.f;
    float m_run = -INFINITY, l_run = 0.f;

    const int ntiles = 2*qt + 2;
    __syncthreads();          // prior phase's smem reads complete
    STAGE(0, 0);
    __syncthreads();

    for (int j = 0; j < ntiles; ++j){
      const int cur = j & 1;
      if (j + 1 < ntiles) STAGE(j+1, cur^1);
      const char* Kc = (const char*)Ks + cur*8192;
      const char* Vc = (const char*)Vs + cur*8192;

      // last tile: waves 0,1 (q rows qb..qb+63) are fully masked -> skip
      const bool fullmask = (j == 2*qt + 1) && (wq < 2);
      if (!fullmask){
        // ---- QK^T ----
        f32x16 st[2];
        #pragma unroll
        for (int i=0;i<2;++i)
          #pragma unroll
          for (int r=0;r<16;++r) st[i][r] = 0.f;
        __builtin_amdgcn_s_setprio(1);
        #pragma unroll
        for (int i=0;i<2;++i){
          #pragma unroll
          for (int kk=0;kk<4;++kk){
            int row = i*32 + l31;
            int colb = (kk*32 + hi*16) ^ ((row & 7) << 4);
            bf16x8 kf = *(const bf16x8*)(Kc + row*128 + colb);
            st[i] = __builtin_amdgcn_mfma_f32_32x32x16_bf16(kf, qf[kk], st[i], 0,0,0);
          }
        }
        __builtin_amdgcn_s_setprio(0);

        // ---- mask + row max (lane-local q) ----
        const int s0 = j*64;
        float mx = -INFINITY;
        if (j >= 2*qt){
          #pragma unroll
          for (int i=0;i<2;++i)
            #pragma unroll
            for (int r=0;r<16;++r){
              int sg = s0 + i*32 + (r&3) + 8*(r>>2) + 4*hi;
              float v = (sg > qg) ? -INFINITY : st[i][r];
              st[i][r] = v;
              mx = fmaxf(mx, v);
            }
        } else {
          #pragma unroll
          for (int i=0;i<2;++i)
            #pragma unroll
            for (int r=0;r<16;++r) mx = fmaxf(mx, st[i][r]);
        }
        mx = xhalf_max(mx);

        // defer-max: rescale only when needed (P bounded by 2^8)
        if (!__all(mx <= m_run + 8.0f)){
          float m_new = fmaxf(m_run, mx);
          float sc = fexp2(m_run - m_new);
          l_run *= sc;
          #pragma unroll
          for (int f=0;f<2;++f)
            #pragma unroll
            for (int r=0;r<16;++r) o[f][r] *= sc;
          m_run = m_new;
        }

        // ---- exp + row sum ----
        float rsum = 0.f;
        #pragma unroll
        for (int i=0;i<2;++i)
          #pragma unroll
          for (int r=0;r<16;++r){
            float p = fexp2(st[i][r] - m_run);
            st[i][r] = p;
            rsum += p;
          }
        l_run += xhalf_sum(rsum);

        // ---- pack P into PV B-fragments: DIRECT (V s-order quad-permuted to match) ----
        u32x4 Bfr[4];
        #pragma unroll
        for (int i=0;i<2;++i){
          Bfr[2*i]   = (u32x4){ cvtpk(st[i][0],  st[i][1]),  cvtpk(st[i][2],  st[i][3]),
                                cvtpk(st[i][4],  st[i][5]),  cvtpk(st[i][6],  st[i][7]) };
          Bfr[2*i+1] = (u32x4){ cvtpk(st[i][8],  st[i][9]),  cvtpk(st[i][10], st[i][11]),
                                cvtpk(st[i][12], st[i][13]), cvtpk(st[i][14], st[i][15]) };
        }

        // ---- O^T += V^T · P^T ----
        __builtin_amdgcn_s_setprio(1);
        #pragma unroll
        for (int ss=0; ss<4; ++ss){
          bf16x8 pb = __builtin_bit_cast(bf16x8, Bfr[ss]);
          #pragma unroll
          for (int f=0; f<2; ++f){
            int row = f*32 + l31;
            int colb = (ss*32 + hi*16) ^ ((row & 7) << 4);
            bf16x8 vf = *(const bf16x8*)(Vc + row*128 + colb);
            o[f] = __builtin_amdgcn_mfma_f32_32x32x16_bf16(vf, pb, o[f], 0,0,0);
          }
        }
        __builtin_amdgcn_s_setprio(0);
      }
      __syncthreads();   // staging for j+1 complete; both buffers safe
    }

    // ---- epilogue: normalize, transpose via LDS, coalesced store ----
    float linv = 1.f / l_run;
    {
      char* Osh = (char*)smem;           // reuse; per-wave region stride 136B x 32 rows
      unsigned base = wq*4352;
      #pragma unroll
      for (int f=0;f<2;++f)
        #pragma unroll
        for (int m=0;m<8;++m){
          unsigned word = cvtpk(o[f][2*m]*linv, o[f][2*m+1]*linv);
          int d0 = (m&1)*2 + 8*(m>>1) + 4*hi + 32*f;
          *(unsigned*)(Osh + base + l31*136 + d0*2) = word;
        }
    }
    __syncthreads();
    {
      int q = tid >> 1, half = tid & 1;    // q 0..127, 64B per thread
      const char* src = (const char*)smem + (q>>5)*4352 + (q&31)*136 + half*64;
      u16* dst = AO + ((size_t)(b_*T_LEN + qb + q))*E_DIM + h*D_H + half*32;
      #pragma unroll
      for (int k=0;k<4;++k)
        *(u16x8*)(dst + k*8) = *(const u16x8*)(src + k*16);
    }
  }
}

extern "C" void kernel_launch(void* const* d_in, const int* in_sizes, int n_in,
                              void* d_out, int out_size, void* d_ws, size_t ws_size,
                              hipStream_t stream){
  const float* query = (const float*)d_in[0];
  const float* key   = (const float*)d_in[1];
  const float* value = (const float*)d_in[2];
  const float* Wq = (const float*)d_in[4];
  const float* bq = (const float*)d_in[5];
  const float* Wk = (const float*)d_in[6];
  const float* bk = (const float*)d_in[7];
  const float* Wv = (const float*)d_in[8];
  const float* bv = (const float*)d_in[9];
  const float* Wo = (const float*)d_in[10];
  const float* bo = (const float*)d_in[11];

  char* ws = (char*)d_ws;
  const size_t SZ_X = (size_t)M_ROWS * E_DIM * 2;   // 16 MB
  const size_t SZ_W = (size_t)E_DIM * E_DIM * 2;    // 2 MB
  u16* Xq  = (u16*)(ws);                    // reused as AO after Q-proj
  u16* Xk  = (u16*)(ws + SZ_X);             // reused as Vt after K-proj
  u16* Xv  = (u16*)(ws + 2*SZ_X);
  u16* Wqb = (u16*)(ws + 3*SZ_X);
  u16* Wkb = (u16*)(ws + 3*SZ_X + 1*SZ_W);
  u16* Wvb = (u16*)(ws + 3*SZ_X + 2*SZ_W);
  u16* Wob = (u16*)(ws + 3*SZ_X + 3*SZ_W);
  u16* Qb  = (u16*)(ws + 3*SZ_X + 4*SZ_W);
  u16* Kb  = (u16*)(ws + 4*SZ_X + 4*SZ_W);
  u16* Vb  = (u16*)(ws + 5*SZ_X + 4*SZ_W);
  u16* Vt  = Xk;
  u16* AO  = Xq;

  const int nX = M_ROWS * E_DIM;
  const int nW = E_DIM * E_DIM;
  cvt_all<<<dim3(1024,1,7), 256, 0, stream>>>(
      query, key, value, Wq, Wk, Wv, Wo,
      Xq, Xk, Xv, Wqb, Wkb, Wvb, Wob, nX, nW);

  const float QSCALE = 0.125f * 1.44269504f;   // 1/sqrt(D) * log2(e): scores in log2 domain
  QKVArgs qa;
  qa.A[0]=Xq;  qa.A[1]=Xk;  qa.A[2]=Xv;
  qa.Bw[0]=Wqb; qa.Bw[1]=Wkb; qa.Bw[2]=Wvb;
  qa.bias[0]=bq; qa.bias[1]=bk; qa.bias[2]=bv;
  qa.scale[0]=QSCALE; qa.scale[1]=1.0f; qa.scale[2]=1.0f;
  qa.out[0]=Qb; qa.out[1]=Kb; qa.out[2]=Vb;
  gemm_qkv<<<dim3(E_DIM/128, M_ROWS/128, 3), 256, 0, stream>>>(qa);
  transpose_v<<<dim3(T_LEN/64, B_SZ*H_N), 256, 0, stream>>>(Vb, Vt);
  attn_fwd<<<dim3(NQT/2, B_SZ*H_N), 256, 0, stream>>>(Qb, Kb, Vt, AO);
  gemm_out<<<dim3(E_DIM/128, M_ROWS/128), 256, 0, stream>>>(AO, Wob, bo, (float*)d_out);
}

// Round 10
// 184.729 us; speedup vs baseline: 1.6381x; 1.1412x over previous
//
#include <hip/hip_runtime.h>

typedef unsigned short u16;
typedef __attribute__((ext_vector_type(8))) __bf16 bf16x8;
typedef __attribute__((ext_vector_type(4))) float f32x4;
typedef __attribute__((ext_vector_type(16))) float f32x16;
typedef __attribute__((ext_vector_type(4))) unsigned short u16x4;
typedef __attribute__((ext_vector_type(8))) unsigned short u16x8;
typedef __attribute__((ext_vector_type(4))) unsigned int u32x4;

#define T_LEN 2048
#define B_SZ 4
#define E_DIM 1024
#define H_N 16
#define D_H 64
#define M_ROWS (T_LEN * B_SZ)   // 8192
#define NQT (T_LEN / 128)       // 16 q-tiles

__device__ __forceinline__ u16 f2bf(float f){
  unsigned u = __builtin_bit_cast(unsigned, f);
  u += 0x7fffu + ((u >> 16) & 1u);
  return (u16)(u >> 16);
}

__device__ __forceinline__ float fexp2(float x){
#if __has_builtin(__builtin_amdgcn_exp2f)
  return __builtin_amdgcn_exp2f(x);
#else
  return exp2f(x);
#endif
}

__device__ __forceinline__ unsigned cvtpk(float lo, float hi){
  unsigned w;
  asm("v_cvt_pk_bf16_f32 %0, %1, %2" : "=v"(w) : "v"(lo), "v"(hi));
  return w;
}
__device__ __forceinline__ float xhalf_max(float x){
  return fmaxf(x, __shfl_xor(x, 32));
}
__device__ __forceinline__ float xhalf_sum(float x){
  return x + __shfl_xor(x, 32);
}

__device__ __forceinline__ void load_lds16(const void* g, void* l){
  __builtin_amdgcn_global_load_lds(
      (const __attribute__((address_space(1))) void*)g,
      (__attribute__((address_space(3))) void*)l, 16, 0, 0);
}

// ---------------- fp32 -> bf16 convert, all 7 tensors in one launch ----------------
__global__ void cvt_all(
    const float* __restrict__ i0, const float* __restrict__ i1, const float* __restrict__ i2,
    const float* __restrict__ i3, const float* __restrict__ i4, const float* __restrict__ i5,
    const float* __restrict__ i6,
    u16* __restrict__ o0, u16* __restrict__ o1, u16* __restrict__ o2,
    u16* __restrict__ o3, u16* __restrict__ o4, u16* __restrict__ o5,
    u16* __restrict__ o6, int nX, int nW)
{
  const int z = blockIdx.z;
  const float* in; u16* out; int n;
  switch (z){
    case 0: in=i0; out=o0; n=nX; break;
    case 1: in=i1; out=o1; n=nX; break;
    case 2: in=i2; out=o2; n=nX; break;
    case 3: in=i3; out=o3; n=nW; break;
    case 4: in=i4; out=o4; n=nW; break;
    case 5: in=i5; out=o5; n=nW; break;
    default: in=i6; out=o6; n=nW; break;
  }
  int idx = (blockIdx.x * blockDim.x + threadIdx.x) * 4;
  int stride = gridDim.x * blockDim.x * 4;
  for (int i = idx; i < n; i += stride){
    float4 v = *(const float4*)(in + i);
    u16x4 o = { f2bf(v.x), f2bf(v.y), f2bf(v.z), f2bf(v.w) };
    *(u16x4*)(out + i) = o;
  }
}

// ======== 8-phase GEMM core: 256x128 tile, BK=64, 512 thr / 8 waves (2M x 4N) ========
// LDS: 3 buffers: A 256x64 (32KB), B 128x64 (16KB) -> 144KB. Counted vmcnt(6).
// T2 swizzle: LDS[row][cb] holds global[row][cb ^ ((row&7)<<4)] (pre-swizzled source).
#define GEMM_LDSU16 73728   // 144KB

__device__ __forceinline__ void stageA8(const u16* __restrict__ A, int m0, int k0, int r,
                                        char* Ab, int tid){
  int c = r*512 + tid;               // [0,2048): 16B chunks of 256x64 panel
  int row = c >> 3;                  // [0,256)
  int colb = ((c & 7) * 16) ^ ((row & 7) << 4);
  load_lds16((const char*)(A + (size_t)(m0 + row)*E_DIM + k0) + colb,
             Ab + (size_t)(r*512 + (tid >> 6)*64)*16);
}
__device__ __forceinline__ void stageB8(const u16* __restrict__ Bt, int n0, int k0, int r,
                                        char* Bb, int tid){
  int c = r*512 + tid;               // [0,1024): 16B chunks of 128x64 panel
  int row = c >> 3;                  // [0,128)
  int colb = ((c & 7) * 16) ^ ((row & 7) << 4);
  load_lds16((const char*)(Bt + (size_t)(n0 + row)*E_DIM + k0) + colb,
             Bb + (size_t)(r*512 + (tid >> 6)*64)*16);
}

__device__ __forceinline__ void gemm8_mainloop(
    const u16* __restrict__ A, const u16* __restrict__ Bt,
    int m0, int n0, u16* smem, f32x4 (&acc)[8][2])
{
  constexpr int NT = E_DIM / 64;     // 16 K-tiles
  const int tid = threadIdx.x;
  const int lane = tid & 63;
  const int w = tid >> 6;
  const int wm = w >> 2, wn = w & 3; // 2M x 4N waves
  const int lr = lane & 15, lg = lane >> 4;
  char* Abase = (char*)smem;             // 3 x 32KB
  char* Bbase = (char*)smem + 98304;     // 3 x 16KB

  #pragma unroll
  for (int i=0;i<8;i++)
    #pragma unroll
    for (int j=0;j<2;j++) acc[i][j] = (f32x4){0.f,0.f,0.f,0.f};

  // prologue: stage tiles 0 and 1
  #pragma unroll
  for (int r=0;r<4;++r) stageA8(A, m0, 0, r, Abase, tid);
  #pragma unroll
  for (int r=0;r<2;++r) stageB8(Bt, n0, 0, r, Bbase, tid);
  #pragma unroll
  for (int r=0;r<4;++r) stageA8(A, m0, 64, r, Abase + 32768, tid);
  #pragma unroll
  for (int r=0;r<2;++r) stageB8(Bt, n0, 64, r, Bbase + 16384, tid);
  asm volatile("s_waitcnt vmcnt(6)\n" ::: "memory");   // tile 0 resident
  __builtin_amdgcn_sched_barrier(0);
  __builtin_amdgcn_s_barrier();

  int buf = 0;
  const int cb0 = (lr & 7) << 4;
  for (int t = 0; t < NT; ++t){
    char* Ac = Abase + buf*32768;
    char* Bc = Bbase + buf*16384;
    int nbuf = buf + 1; if (nbuf == 3) nbuf = 0;
    int sbuf = nbuf + 1; if (sbuf == 3) sbuf = 0;    // (t+2)%3 — freed after tile t-1
    char* As = Abase + sbuf*32768;
    char* Bs = Bbase + sbuf*16384;
    const int k2 = (t + 2) * 64;
    const bool has2 = (t + 2 < NT);
    bf16x8 bfrag[2][2];

    #pragma unroll
    for (int p = 0; p < 4; ++p){
      // ---- ds_read this phase's A sub-tile (rows 2p,2p+1 of the wave's 8) ----
      const int r0 = wm*128 + (2*p)*16 + lr;
      const int r1 = r0 + 16;
      bf16x8 a00 = *(const bf16x8*)(Ac + r0*128 + ((lg*16)      ^ cb0));
      bf16x8 a01 = *(const bf16x8*)(Ac + r0*128 + ((lg*16 + 64) ^ cb0));
      bf16x8 a10 = *(const bf16x8*)(Ac + r1*128 + ((lg*16)      ^ cb0));
      bf16x8 a11 = *(const bf16x8*)(Ac + r1*128 + ((lg*16 + 64) ^ cb0));
      if (p == 0){
        #pragma unroll
        for (int j=0;j<2;++j){
          int rb = wn*32 + j*16 + lr;
          bfrag[j][0] = *(const bf16x8*)(Bc + rb*128 + ((lg*16)      ^ cb0));
          bfrag[j][1] = *(const bf16x8*)(Bc + rb*128 + ((lg*16 + 64) ^ cb0));
        }
      }
      // ---- spread stage issues for tile t+2 ----
      if (has2){
        if (p == 0){ stageA8(A, m0, k2, 0, As, tid); stageA8(A, m0, k2, 1, As, tid); }
        else if (p == 1){ stageA8(A, m0, k2, 2, As, tid); stageA8(A, m0, k2, 3, As, tid); }
        else if (p == 2){ stageB8(Bt, n0, k2, 0, Bs, tid); stageB8(Bt, n0, k2, 1, Bs, tid); }
      }
      __builtin_amdgcn_s_barrier();
      asm volatile("s_waitcnt lgkmcnt(0)\n" ::: "memory");
      __builtin_amdgcn_sched_barrier(0);
      __builtin_amdgcn_s_setprio(1);
      const int i0 = 2*p, i1 = 2*p + 1;
      acc[i0][0] = __builtin_amdgcn_mfma_f32_16x16x32_bf16(a00, bfrag[0][0], acc[i0][0], 0,0,0);
      acc[i0][0] = __builtin_amdgcn_mfma_f32_16x16x32_bf16(a01, bfrag[0][1], acc[i0][0], 0,0,0);
      acc[i0][1] = __builtin_amdgcn_mfma_f32_16x16x32_bf16(a00, bfrag[1][0], acc[i0][1], 0,0,0);
      acc[i0][1] = __builtin_amdgcn_mfma_f32_16x16x32_bf16(a01, bfrag[1][1], acc[i0][1], 0,0,0);
      acc[i1][0] = __builtin_amdgcn_mfma_f32_16x16x32_bf16(a10, bfrag[0][0], acc[i1][0], 0,0,0);
      acc[i1][0] = __builtin_amdgcn_mfma_f32_16x16x32_bf16(a11, bfrag[0][1], acc[i1][0], 0,0,0);
      acc[i1][1] = __builtin_amdgcn_mfma_f32_16x16x32_bf16(a10, bfrag[1][0], acc[i1][1], 0,0,0);
      acc[i1][1] = __builtin_amdgcn_mfma_f32_16x16x32_bf16(a11, bfrag[1][1], acc[i1][1], 0,0,0);
      __builtin_amdgcn_s_setprio(0);
      if (p == 3){
        // counted drain: allow tile t+2's 6 loads in flight; retire tile t+1's
        if (t < NT-2)       asm volatile("s_waitcnt vmcnt(6)\n" ::: "memory");
        else if (t == NT-2) asm volatile("s_waitcnt vmcnt(0)\n" ::: "memory");
        __builtin_amdgcn_sched_barrier(0);
      }
      __builtin_amdgcn_s_barrier();
    }
    buf = nbuf;
  }
  __builtin_amdgcn_sched_barrier(0);
}

// XCD-bijective remap: same-XCD blocks share A-panels (A fetched once per chip)
__device__ __forceinline__ void xcd_remap_gemm(int &m0, int &n0){
  int L = blockIdx.y * 8 + blockIdx.x;     // 256 blocks
  int c = L & 7, i = L >> 3;               // i in [0,32)
  int by = c*4 + (i & 3);                  // [0,32)
  int bx = i >> 2;                         // [0,8)
  m0 = by * 256; n0 = bx * 128;
}

struct QKVArgs {
  const u16* A[3]; const u16* Bw[3]; const float* bias[3];
  float scale[3]; u16* out[3];
};

// Q/K/V projections. Writes bf16 [B,H,L,D].
__global__ __launch_bounds__(512, 1) void gemm_qkv(QKVArgs args){
  __shared__ __align__(16) u16 smem[GEMM_LDSU16];
  const int z = blockIdx.z;
  int m0, n0; xcd_remap_gemm(m0, n0);
  f32x4 acc[8][2];
  gemm8_mainloop(args.A[z], args.Bw[z], m0, n0, smem, acc);

  const int lane = threadIdx.x & 63;
  const int w = threadIdx.x >> 6;
  const int wm = w >> 2, wn = w & 3;
  const int lr = lane & 15, lg = lane >> 4;
  const float* bias = args.bias[z];
  const float scale = args.scale[z];
  u16* outB = args.out[z];
  #pragma unroll
  for (int i=0;i<8;i++)
    #pragma unroll
    for (int j=0;j<2;j++)
      #pragma unroll
      for (int q=0;q<4;q++){
        int m = m0 + wm*128 + i*16 + lg*4 + q;
        int n = n0 + wn*32 + j*16 + lr;
        float v = (acc[i][j][q] + bias[n]) * scale;
        int t = m >> 2, b = m & 3;             // rows of [L,B,E]: m = t*B + b
        int h = n >> 6, d = n & 63;
        outB[ ((size_t)(b*H_N + h)*T_LEN + t)*D_H + d ] = f2bf(v);
      }
}

// Output projection: AO [B,T,E] -> d_out [T,B,E] fp32
__global__ __launch_bounds__(512, 1) void gemm_out(
    const u16* __restrict__ A, const u16* __restrict__ Bt,
    const float* __restrict__ bias, float* __restrict__ outF)
{
  __shared__ __align__(16) u16 smem[GEMM_LDSU16];
  int m0, n0; xcd_remap_gemm(m0, n0);
  f32x4 acc[8][2];
  gemm8_mainloop(A, Bt, m0, n0, smem, acc);

  const int lane = threadIdx.x & 63;
  const int w = threadIdx.x >> 6;
  const int wm = w >> 2, wn = w & 3;
  const int lr = lane & 15, lg = lane >> 4;
  #pragma unroll
  for (int i=0;i<8;i++)
    #pragma unroll
    for (int j=0;j<2;j++)
      #pragma unroll
      for (int q=0;q<4;q++){
        int m = m0 + wm*128 + i*16 + lg*4 + q;
        int n = n0 + wn*32 + j*16 + lr;
        float v = acc[i][j][q] + bias[n];
        int b = m >> 11, t = m & 2047;         // rows of AO [B,T,E]: m = b*T + t
        outF[ (size_t)(t*B_SZ + b)*E_DIM + n ] = v;
      }
}

// ---------------- V transpose: [B,H,S,D] -> [B,H,D,S], s quad-permuted ----------------
__global__ __launch_bounds__(256) void transpose_v(const u16* __restrict__ Vb, u16* __restrict__ Vt){
  __shared__ u16 tile[64][65];
  int bh = blockIdx.y, s0 = blockIdx.x * 64;
  const u16* src = Vb + ((size_t)bh*T_LEN + s0)*D_H;
  u16* dst = Vt + (size_t)bh*D_H*T_LEN + s0;
  int tid = threadIdx.x;
  #pragma unroll
  for (int r=0;r<2;++r){
    int c = r*256 + tid;
    int s = c >> 3, d0 = (c & 7)*8;
    u16x8 v = *(const u16x8*)(src + (size_t)s*D_H + d0);
    #pragma unroll
    for (int j=0;j<8;j++) tile[d0+j][s] = v[j];
  }
  __syncthreads();
  #pragma unroll
  for (int r=0;r<2;++r){
    int c = r*256 + tid;
    int d = c >> 3, s1 = (c & 7)*8;
    u16x8 v;
    #pragma unroll
    for (int j=0;j<8;j++){
      int p = s1 + j;
      int sp = (p & ~12) | ((p & 4) << 1) | ((p & 8) >> 1);   // involution
      v[j] = tile[d][sp];
    }
    *(u16x8*)(dst + (size_t)d*T_LEN + s1) = v;
  }
}

// ---------------- causal flash attention, 32x32 MFMA, QBLK=128, KVBLK=64 ----------------
// Two q-tiles per block (constant work); XCD remap so same-XCD blocks share K/V.
__global__ __launch_bounds__(256) void attn_fwd(
    const u16* __restrict__ Qb, const u16* __restrict__ Kb,
    const u16* __restrict__ Vt, u16* __restrict__ AO)
{
  __shared__ __align__(16) u16 smem[4*64*64];
  u16* Ks = smem;
  u16* Vs = smem + 2*64*64;
  const int tid = threadIdx.x;
  const int lane = tid & 63;
  const int wq = tid >> 6;
  const int l31 = lane & 31;
  const int hi = lane >> 5;
  int bh, px;
  {
    int L = blockIdx.y * 8 + blockIdx.x;
    int c = L & 7, i2 = L >> 3;
    bh = c*8 + (i2 & 7);
    px = i2 >> 3;
  }
  const u16* Kbase = Kb + (size_t)bh * T_LEN * D_H;
  const u16* Vbase = Vt + (size_t)bh * D_H * T_LEN;
  const int b_ = bh >> 4, h = bh & 15;

  auto STAGE = [&](int j, int b){
    int s0 = j * 64;
    #pragma unroll
    for (int r=0;r<2;++r){
      int c = r*256 + tid;
      int row = c >> 3;
      int colb = (c & 7) * 16;
      int scolb = colb ^ ((row & 7) << 4);
      load_lds16((const char*)(Kbase + (size_t)(s0 + row)*D_H) + scolb,
                 (char*)Ks + b*8192 + (r*256 + wq*64)*16);
      load_lds16((const char*)(Vbase + (size_t)row*T_LEN + s0) + scolb,
                 (char*)Vs + b*8192 + (r*256 + wq*64)*16);
    }
  };

  #pragma unroll 1
  for (int ph = 0; ph < 2; ++ph){
    const int qt = ph ? px : (NQT - 1 - px);
    const int qb = qt * 128;
    const int qg = qb + wq*32 + l31;

    bf16x8 qf[4];
    {
      const u16* qp = Qb + (size_t)bh*T_LEN*D_H + (size_t)qg*D_H + hi*8;
      #pragma unroll
      for (int kk=0;kk<4;++kk) qf[kk] = *(const bf16x8*)(qp + kk*16);
    }

    f32x16 o[2];
    #pragma unroll
    for (int f=0;f<2;++f)
      #pragma unroll
      for (int r=0;r<16;++r) o[f][r] = 0.f;
    float m_run = -INFINITY, l_run = 0.f;

    const int ntiles = 2*qt + 2;
    __syncthreads();
    STAGE(0, 0);
    __syncthreads();

    for (int j = 0; j < ntiles; ++j){
      const int cur = j & 1;
      if (j + 1 < ntiles) STAGE(j+1, cur^1);
      const char* Kc = (const char*)Ks + cur*8192;
      const char* Vc = (const char*)Vs + cur*8192;

      const bool fullmask = (j == 2*qt + 1) && (wq < 2);
      if (!fullmask){
        f32x16 st[2];
        #pragma unroll
        for (int i=0;i<2;++i)
          #pragma unroll
          for (int r=0;r<16;++r) st[i][r] = 0.f;
        __builtin_amdgcn_s_setprio(1);
        #pragma unroll
        for (int i=0;i<2;++i){
          #pragma unroll
          for (int kk=0;kk<4;++kk){
            int row = i*32 + l31;
            int colb = (kk*32 + hi*16) ^ ((row & 7) << 4);
            bf16x8 kf = *(const bf16x8*)(Kc + row*128 + colb);
            st[i] = __builtin_amdgcn_mfma_f32_32x32x16_bf16(kf, qf[kk], st[i], 0,0,0);
          }
        }
        __builtin_amdgcn_s_setprio(0);

        const int s0 = j*64;
        float mx = -INFINITY;
        if (j >= 2*qt){
          #pragma unroll
          for (int i=0;i<2;++i)
            #pragma unroll
            for (int r=0;r<16;++r){
              int sg = s0 + i*32 + (r&3) + 8*(r>>2) + 4*hi;
              float v = (sg > qg) ? -INFINITY : st[i][r];
              st[i][r] = v;
              mx = fmaxf(mx, v);
            }
        } else {
          #pragma unroll
          for (int i=0;i<2;++i)
            #pragma unroll
            for (int r=0;r<16;++r) mx = fmaxf(mx, st[i][r]);
        }
        mx = xhalf_max(mx);

        if (!__all(mx <= m_run + 8.0f)){
          float m_new = fmaxf(m_run, mx);
          float sc = fexp2(m_run - m_new);
          l_run *= sc;
          #pragma unroll
          for (int f=0;f<2;++f)
            #pragma unroll
            for (int r=0;r<16;++r) o[f][r] *= sc;
          m_run = m_new;
        }

        float rsum = 0.f;
        #pragma unroll
        for (int i=0;i<2;++i)
          #pragma unroll
          for (int r=0;r<16;++r){
            float p = fexp2(st[i][r] - m_run);
            st[i][r] = p;
            rsum += p;
          }
        l_run += xhalf_sum(rsum);

        u32x4 Bfr[4];
        #pragma unroll
        for (int i=0;i<2;++i){
          Bfr[2*i]   = (u32x4){ cvtpk(st[i][0],  st[i][1]),  cvtpk(st[i][2],  st[i][3]),
                                cvtpk(st[i][4],  st[i][5]),  cvtpk(st[i][6],  st[i][7]) };
          Bfr[2*i+1] = (u32x4){ cvtpk(st[i][8],  st[i][9]),  cvtpk(st[i][10], st[i][11]),
                                cvtpk(st[i][12], st[i][13]), cvtpk(st[i][14], st[i][15]) };
        }

        __builtin_amdgcn_s_setprio(1);
        #pragma unroll
        for (int ss=0; ss<4; ++ss){
          bf16x8 pb = __builtin_bit_cast(bf16x8, Bfr[ss]);
          #pragma unroll
          for (int f=0; f<2; ++f){
            int row = f*32 + l31;
            int colb = (ss*32 + hi*16) ^ ((row & 7) << 4);
            bf16x8 vf = *(const bf16x8*)(Vc + row*128 + colb);
            o[f] = __builtin_amdgcn_mfma_f32_32x32x16_bf16(vf, pb, o[f], 0,0,0);
          }
        }
        __builtin_amdgcn_s_setprio(0);
      }
      __syncthreads();
    }

    float linv = 1.f / l_run;
    {
      char* Osh = (char*)smem;
      unsigned base = wq*4352;
      #pragma unroll
      for (int f=0;f<2;++f)
        #pragma unroll
        for (int m=0;m<8;++m){
          unsigned word = cvtpk(o[f][2*m]*linv, o[f][2*m+1]*linv);
          int d0 = (m&1)*2 + 8*(m>>1) + 4*hi + 32*f;
          *(unsigned*)(Osh + base + l31*136 + d0*2) = word;
        }
    }
    __syncthreads();
    {
      int q = tid >> 1, half = tid & 1;
      const char* src = (const char*)smem + (q>>5)*4352 + (q&31)*136 + half*64;
      u16* dst = AO + ((size_t)(b_*T_LEN + qb + q))*E_DIM + h*D_H + half*32;
      #pragma unroll
      for (int k=0;k<4;++k)
        *(u16x8*)(dst + k*8) = *(const u16x8*)(src + k*16);
    }
  }
}

extern "C" void kernel_launch(void* const* d_in, const int* in_sizes, int n_in,
                              void* d_out, int out_size, void* d_ws, size_t ws_size,
                              hipStream_t stream){
  const float* query = (const float*)d_in[0];
  const float* key   = (const float*)d_in[1];
  const float* value = (const float*)d_in[2];
  const float* Wq = (const float*)d_in[4];
  const float* bq = (const float*)d_in[5];
  const float* Wk = (const float*)d_in[6];
  const float* bk = (const float*)d_in[7];
  const float* Wv = (const float*)d_in[8];
  const float* bv = (const float*)d_in[9];
  const float* Wo = (const float*)d_in[10];
  const float* bo = (const float*)d_in[11];

  char* ws = (char*)d_ws;
  const size_t SZ_X = (size_t)M_ROWS * E_DIM * 2;   // 16 MB
  const size_t SZ_W = (size_t)E_DIM * E_DIM * 2;    // 2 MB
  u16* Xq  = (u16*)(ws);                    // reused as AO after Q-proj
  u16* Xk  = (u16*)(ws + SZ_X);             // reused as Vt after K-proj
  u16* Xv  = (u16*)(ws + 2*SZ_X);
  u16* Wqb = (u16*)(ws + 3*SZ_X);
  u16* Wkb = (u16*)(ws + 3*SZ_X + 1*SZ_W);
  u16* Wvb = (u16*)(ws + 3*SZ_X + 2*SZ_W);
  u16* Wob = (u16*)(ws + 3*SZ_X + 3*SZ_W);
  u16* Qb  = (u16*)(ws + 3*SZ_X + 4*SZ_W);
  u16* Kb  = (u16*)(ws + 4*SZ_X + 4*SZ_W);
  u16* Vb  = (u16*)(ws + 5*SZ_X + 4*SZ_W);
  u16* Vt  = Xk;
  u16* AO  = Xq;

  const int nX = M_ROWS * E_DIM;
  const int nW = E_DIM * E_DIM;
  cvt_all<<<dim3(1024,1,7), 256, 0, stream>>>(
      query, key, value, Wq, Wk, Wv, Wo,
      Xq, Xk, Xv, Wqb, Wkb, Wvb, Wob, nX, nW);

  const float QSCALE = 0.125f * 1.44269504f;   // 1/sqrt(D) * log2(e)
  QKVArgs qa;
  qa.A[0]=Xq;  qa.A[1]=Xk;  qa.A[2]=Xv;
  qa.Bw[0]=Wqb; qa.Bw[1]=Wkb; qa.Bw[2]=Wvb;
  qa.bias[0]=bq; qa.bias[1]=bk; qa.bias[2]=bv;
  qa.scale[0]=QSCALE; qa.scale[1]=1.0f; qa.scale[2]=1.0f;
  qa.out[0]=Qb; qa.out[1]=Kb; qa.out[2]=Vb;
  gemm_qkv<<<dim3(8, M_ROWS/256, 3), 512, 0, stream>>>(qa);
  transpose_v<<<dim3(T_LEN/64, B_SZ*H_N), 256, 0, stream>>>(Vb, Vt);
  attn_fwd<<<dim3(NQT/2, B_SZ*H_N), 256, 0, stream>>>(Qb, Kb, Vt, AO);
  gemm_out<<<dim3(8, M_ROWS/256), 512, 0, stream>>>(AO, Wob, bo, (float*)d_out);
}

// Round 11
// 180.708 us; speedup vs baseline: 1.6745x; 1.0223x over previous
//
#include <hip/hip_runtime.h>

typedef unsigned short u16;
typedef __attribute__((ext_vector_type(8))) __bf16 bf16x8;
typedef __attribute__((ext_vector_type(4))) float f32x4;
typedef __attribute__((ext_vector_type(16))) float f32x16;
typedef __attribute__((ext_vector_type(4))) unsigned short u16x4;
typedef __attribute__((ext_vector_type(8))) unsigned short u16x8;
typedef __attribute__((ext_vector_type(4))) unsigned int u32x4;

#define T_LEN 2048
#define B_SZ 4
#define E_DIM 1024
#define H_N 16
#define D_H 64
#define M_ROWS (T_LEN * B_SZ)   // 8192
#define NQT (T_LEN / 128)       // 16 q-tiles

__device__ __forceinline__ u16 f2bf(float f){
  unsigned u = __builtin_bit_cast(unsigned, f);
  u += 0x7fffu + ((u >> 16) & 1u);
  return (u16)(u >> 16);
}

__device__ __forceinline__ float fexp2(float x){
#if __has_builtin(__builtin_amdgcn_exp2f)
  return __builtin_amdgcn_exp2f(x);
#else
  return exp2f(x);
#endif
}

__device__ __forceinline__ unsigned cvtpk(float lo, float hi){
  unsigned w;
  asm("v_cvt_pk_bf16_f32 %0, %1, %2" : "=v"(w) : "v"(lo), "v"(hi));
  return w;
}
__device__ __forceinline__ float xhalf_max(float x){
  return fmaxf(x, __shfl_xor(x, 32));
}
__device__ __forceinline__ float xhalf_sum(float x){
  return x + __shfl_xor(x, 32);
}

__device__ __forceinline__ void load_lds16(const void* g, void* l){
  __builtin_amdgcn_global_load_lds(
      (const __attribute__((address_space(1))) void*)g,
      (__attribute__((address_space(3))) void*)l, 16, 0, 0);
}

// ---------------- fp32 -> bf16 convert, all 7 tensors in one launch ----------------
__global__ void cvt_all(
    const float* __restrict__ i0, const float* __restrict__ i1, const float* __restrict__ i2,
    const float* __restrict__ i3, const float* __restrict__ i4, const float* __restrict__ i5,
    const float* __restrict__ i6,
    u16* __restrict__ o0, u16* __restrict__ o1, u16* __restrict__ o2,
    u16* __restrict__ o3, u16* __restrict__ o4, u16* __restrict__ o5,
    u16* __restrict__ o6, int nX, int nW)
{
  const int z = blockIdx.z;
  const float* in; u16* out; int n;
  switch (z){
    case 0: in=i0; out=o0; n=nX; break;
    case 1: in=i1; out=o1; n=nX; break;
    case 2: in=i2; out=o2; n=nX; break;
    case 3: in=i3; out=o3; n=nW; break;
    case 4: in=i4; out=o4; n=nW; break;
    case 5: in=i5; out=o5; n=nW; break;
    default: in=i6; out=o6; n=nW; break;
  }
  int idx = (blockIdx.x * blockDim.x + threadIdx.x) * 4;
  int stride = gridDim.x * blockDim.x * 4;
  for (int i = idx; i < n; i += stride){
    float4 v = *(const float4*)(in + i);
    u16x4 o = { f2bf(v.x), f2bf(v.y), f2bf(v.z), f2bf(v.w) };
    *(u16x4*)(out + i) = o;
  }
}

// ======== GEMM core: 128x128 tile, BK=32, 256 thr / 4 waves (2x2), 4-buf LDS ========
// Depth-2 prefetch, counted vmcnt(4), ONE barrier per K-tile, 2 blocks/CU (64KB LDS).
// Swizzle (64B rows): col ^= ((row>>2)&3)<<4 on pre-swizzled source AND reads (<=2-way).
#define G4_LDSU16 32768   // 64KB total: A 4x8KB @0, B 4x8KB @32768B

__device__ __forceinline__ void stageG(const u16* __restrict__ G, int r0g, int k0,
                                       char* base, int buf, int tid){
  #pragma unroll
  for (int r=0;r<2;++r){
    int c = r*256 + tid;
    int row = c >> 2;
    int colb = ((c & 3) * 16) ^ (((row >> 2) & 3) << 4);
    load_lds16((const char*)(G + (size_t)(r0g + row)*E_DIM + k0) + colb,
               base + buf*8192 + (size_t)(r*256 + (tid >> 6)*64)*16);
  }
}

__device__ __forceinline__ void gemm4_mainloop(
    const u16* __restrict__ A, const u16* __restrict__ Bt,
    int m0, int n0, u16* smem, f32x4 (&acc)[4][4])
{
  constexpr int NT = E_DIM / 32;     // 32 K-tiles
  const int tid = threadIdx.x;
  const int lane = tid & 63;
  const int w = tid >> 6;
  const int wr = w >> 1, wc = w & 1;
  const int lr = lane & 15, lg = lane >> 4;
  char* Abase = (char*)smem;
  char* Bbase = (char*)smem + 32768;

  #pragma unroll
  for (int i=0;i<4;i++)
    #pragma unroll
    for (int j=0;j<4;j++) acc[i][j] = (f32x4){0.f,0.f,0.f,0.f};

  // prologue: tiles 0 and 1 (4 loads each)
  stageG(A,  m0, 0,  Abase, 0, tid);
  stageG(Bt, n0, 0,  Bbase, 0, tid);
  stageG(A,  m0, 32, Abase, 1, tid);
  stageG(Bt, n0, 32, Bbase, 1, tid);
  asm volatile("s_waitcnt vmcnt(4)\n" ::: "memory");   // tile 0 resident
  __builtin_amdgcn_sched_barrier(0);
  __builtin_amdgcn_s_barrier();

  // frag byte-col (swizzled): lane reads [row][lg*8..+8) bf16
  const int cbx = (lg*16) ^ (((lr >> 2) & 3) << 4);

  for (int t = 0; t < NT; ++t){
    const int buf = t & 3;
    if (t + 2 < NT){                 // stage t+2 into (t+2)&3 (read at t-2, safe)
      stageG(A,  m0, (t+2)*32, Abase, (t+2) & 3, tid);
      stageG(Bt, n0, (t+2)*32, Bbase, (t+2) & 3, tid);
    }
    char* Ac = Abase + buf*8192;
    char* Bc = Bbase + buf*8192;
    bf16x8 af[4], bfr[4];
    #pragma unroll
    for (int i=0;i<4;i++){
      af[i]  = *(const bf16x8*)(Ac + (wr*64 + i*16 + lr)*64 + cbx);
      bfr[i] = *(const bf16x8*)(Bc + (wc*64 + i*16 + lr)*64 + cbx);
    }
    asm volatile("s_waitcnt lgkmcnt(0)\n" ::: "memory");
    __builtin_amdgcn_sched_barrier(0);
    __builtin_amdgcn_s_setprio(1);
    #pragma unroll
    for (int i=0;i<4;i++)
      #pragma unroll
      for (int j=0;j<4;j++)
        acc[i][j] = __builtin_amdgcn_mfma_f32_16x16x32_bf16(af[i], bfr[j], acc[i][j], 0,0,0);
    __builtin_amdgcn_s_setprio(0);
    // counted drain: keep t+2's 4 loads in flight; retire t+1's
    if (t + 2 < NT)      asm volatile("s_waitcnt vmcnt(4)\n" ::: "memory");
    else if (t + 1 < NT) asm volatile("s_waitcnt vmcnt(0)\n" ::: "memory");
    __builtin_amdgcn_sched_barrier(0);
    __builtin_amdgcn_s_barrier();
  }
}

// XCD remap: 512 blocks/GEMM, XCD c owns m-panels [8c,8c+8) x all 8 n-tiles
// (A 8x256KB = 2MB + W 2MB per XCD L2)
__device__ __forceinline__ void xcd_remap_gemm(int &m0, int &n0){
  int L = blockIdx.y * 8 + blockIdx.x;     // [0,512)
  int c = L & 7, i = L >> 3;               // i in [0,64)
  int by = c*8 + (i & 7);                  // [0,64)
  int bx = i >> 3;                         // [0,8)
  m0 = by * 128; n0 = bx * 128;
}

struct QKVArgs {
  const u16* A[3]; const u16* Bw[3]; const float* bias[3];
  float scale[3]; u16* out[3];
};

// Q/K/V projections. Writes bf16 [B,H,L,D].
__global__ __launch_bounds__(256) void gemm_qkv(QKVArgs args){
  __shared__ __align__(16) u16 smem[G4_LDSU16];
  const int z = blockIdx.z;
  int m0, n0; xcd_remap_gemm(m0, n0);
  f32x4 acc[4][4];
  gemm4_mainloop(args.A[z], args.Bw[z], m0, n0, smem, acc);

  const int lane = threadIdx.x & 63;
  const int w = threadIdx.x >> 6;
  const int wr = w >> 1, wc = w & 1;
  const int lr = lane & 15, lg = lane >> 4;
  const float* bias = args.bias[z];
  const float scale = args.scale[z];
  u16* outB = args.out[z];
  #pragma unroll
  for (int i=0;i<4;i++)
    #pragma unroll
    for (int j=0;j<4;j++)
      #pragma unroll
      for (int q=0;q<4;q++){
        int m = m0 + wr*64 + i*16 + lg*4 + q;
        int n = n0 + wc*64 + j*16 + lr;
        float v = (acc[i][j][q] + bias[n]) * scale;
        int t = m >> 2, b = m & 3;             // rows of [L,B,E]: m = t*B + b
        int h = n >> 6, d = n & 63;
        outB[ ((size_t)(b*H_N + h)*T_LEN + t)*D_H + d ] = f2bf(v);
      }
}

// Output projection: AO [B,T,E] -> d_out [T,B,E] fp32
__global__ __launch_bounds__(256) void gemm_out(
    const u16* __restrict__ A, const u16* __restrict__ Bt,
    const float* __restrict__ bias, float* __restrict__ outF)
{
  __shared__ __align__(16) u16 smem[G4_LDSU16];
  int m0, n0; xcd_remap_gemm(m0, n0);
  f32x4 acc[4][4];
  gemm4_mainloop(A, Bt, m0, n0, smem, acc);

  const int lane = threadIdx.x & 63;
  const int w = threadIdx.x >> 6;
  const int wr = w >> 1, wc = w & 1;
  const int lr = lane & 15, lg = lane >> 4;
  #pragma unroll
  for (int i=0;i<4;i++)
    #pragma unroll
    for (int j=0;j<4;j++)
      #pragma unroll
      for (int q=0;q<4;q++){
        int m = m0 + wr*64 + i*16 + lg*4 + q;
        int n = n0 + wc*64 + j*16 + lr;
        float v = acc[i][j][q] + bias[n];
        int b = m >> 11, t = m & 2047;         // rows of AO [B,T,E]: m = b*T + t
        outF[ (size_t)(t*B_SZ + b)*E_DIM + n ] = v;
      }
}

// ---------------- V transpose: [B,H,S,D] -> [B,H,D,S], s quad-permuted ----------------
__global__ __launch_bounds__(256) void transpose_v(const u16* __restrict__ Vb, u16* __restrict__ Vt){
  __shared__ u16 tile[64][65];
  int bh = blockIdx.y, s0 = blockIdx.x * 64;
  const u16* src = Vb + ((size_t)bh*T_LEN + s0)*D_H;
  u16* dst = Vt + (size_t)bh*D_H*T_LEN + s0;
  int tid = threadIdx.x;
  #pragma unroll
  for (int r=0;r<2;++r){
    int c = r*256 + tid;
    int s = c >> 3, d0 = (c & 7)*8;
    u16x8 v = *(const u16x8*)(src + (size_t)s*D_H + d0);
    #pragma unroll
    for (int j=0;j<8;j++) tile[d0+j][s] = v[j];
  }
  __syncthreads();
  #pragma unroll
  for (int r=0;r<2;++r){
    int c = r*256 + tid;
    int d = c >> 3, s1 = (c & 7)*8;
    u16x8 v;
    #pragma unroll
    for (int j=0;j<8;j++){
      int p = s1 + j;
      int sp = (p & ~12) | ((p & 4) << 1) | ((p & 8) >> 1);   // involution
      v[j] = tile[d][sp];
    }
    *(u16x8*)(dst + (size_t)d*T_LEN + s1) = v;
  }
}

// ---------------- causal flash attention, 32x32 MFMA, QBLK=128, KVBLK=64 ----------------
// Two q-tiles per block (constant work); XCD remap so same-XCD blocks share K/V.
__global__ __launch_bounds__(256) void attn_fwd(
    const u16* __restrict__ Qb, const u16* __restrict__ Kb,
    const u16* __restrict__ Vt, u16* __restrict__ AO)
{
  __shared__ __align__(16) u16 smem[4*64*64];
  u16* Ks = smem;
  u16* Vs = smem + 2*64*64;
  const int tid = threadIdx.x;
  const int lane = tid & 63;
  const int wq = tid >> 6;
  const int l31 = lane & 31;
  const int hi = lane >> 5;
  int bh, px;
  {
    int L = blockIdx.y * 8 + blockIdx.x;
    int c = L & 7, i2 = L >> 3;
    bh = c*8 + (i2 & 7);
    px = i2 >> 3;
  }
  const u16* Kbase = Kb + (size_t)bh * T_LEN * D_H;
  const u16* Vbase = Vt + (size_t)bh * D_H * T_LEN;
  const int b_ = bh >> 4, h = bh & 15;

  auto STAGE = [&](int j, int b){
    int s0 = j * 64;
    #pragma unroll
    for (int r=0;r<2;++r){
      int c = r*256 + tid;
      int row = c >> 3;
      int colb = (c & 7) * 16;
      int scolb = colb ^ ((row & 7) << 4);
      load_lds16((const char*)(Kbase + (size_t)(s0 + row)*D_H) + scolb,
                 (char*)Ks + b*8192 + (r*256 + wq*64)*16);
      load_lds16((const char*)(Vbase + (size_t)row*T_LEN + s0) + scolb,
                 (char*)Vs + b*8192 + (r*256 + wq*64)*16);
    }
  };

  #pragma unroll 1
  for (int ph = 0; ph < 2; ++ph){
    const int qt = ph ? px : (NQT - 1 - px);
    const int qb = qt * 128;
    const int qg = qb + wq*32 + l31;

    bf16x8 qf[4];
    {
      const u16* qp = Qb + (size_t)bh*T_LEN*D_H + (size_t)qg*D_H + hi*8;
      #pragma unroll
      for (int kk=0;kk<4;++kk) qf[kk] = *(const bf16x8*)(qp + kk*16);
    }

    f32x16 o[2];
    #pragma unroll
    for (int f=0;f<2;++f)
      #pragma unroll
      for (int r=0;r<16;++r) o[f][r] = 0.f;
    float m_run = -INFINITY, l_run = 0.f;

    const int ntiles = 2*qt + 2;
    __syncthreads();
    STAGE(0, 0);
    __syncthreads();

    for (int j = 0; j < ntiles; ++j){
      const int cur = j & 1;
      if (j + 1 < ntiles) STAGE(j+1, cur^1);
      const char* Kc = (const char*)Ks + cur*8192;
      const char* Vc = (const char*)Vs + cur*8192;

      const bool fullmask = (j == 2*qt + 1) && (wq < 2);
      if (!fullmask){
        f32x16 st[2];
        #pragma unroll
        for (int i=0;i<2;++i)
          #pragma unroll
          for (int r=0;r<16;++r) st[i][r] = 0.f;
        __builtin_amdgcn_s_setprio(1);
        #pragma unroll
        for (int i=0;i<2;++i){
          #pragma unroll
          for (int kk=0;kk<4;++kk){
            int row = i*32 + l31;
            int colb = (kk*32 + hi*16) ^ ((row & 7) << 4);
            bf16x8 kf = *(const bf16x8*)(Kc + row*128 + colb);
            st[i] = __builtin_amdgcn_mfma_f32_32x32x16_bf16(kf, qf[kk], st[i], 0,0,0);
          }
        }
        __builtin_amdgcn_s_setprio(0);

        const int s0 = j*64;
        float mx = -INFINITY;
        if (j >= 2*qt){
          #pragma unroll
          for (int i=0;i<2;++i)
            #pragma unroll
            for (int r=0;r<16;++r){
              int sg = s0 + i*32 + (r&3) + 8*(r>>2) + 4*hi;
              float v = (sg > qg) ? -INFINITY : st[i][r];
              st[i][r] = v;
              mx = fmaxf(mx, v);
            }
        } else {
          #pragma unroll
          for (int i=0;i<2;++i)
            #pragma unroll
            for (int r=0;r<16;++r) mx = fmaxf(mx, st[i][r]);
        }
        mx = xhalf_max(mx);

        if (!__all(mx <= m_run + 8.0f)){
          float m_new = fmaxf(m_run, mx);
          float sc = fexp2(m_run - m_new);
          l_run *= sc;
          #pragma unroll
          for (int f=0;f<2;++f)
            #pragma unroll
            for (int r=0;r<16;++r) o[f][r] *= sc;
          m_run = m_new;
        }

        float rsum = 0.f;
        #pragma unroll
        for (int i=0;i<2;++i)
          #pragma unroll
          for (int r=0;r<16;++r){
            float p = fexp2(st[i][r] - m_run);
            st[i][r] = p;
            rsum += p;
          }
        l_run += xhalf_sum(rsum);

        u32x4 Bfr[4];
        #pragma unroll
        for (int i=0;i<2;++i){
          Bfr[2*i]   = (u32x4){ cvtpk(st[i][0],  st[i][1]),  cvtpk(st[i][2],  st[i][3]),
                                cvtpk(st[i][4],  st[i][5]),  cvtpk(st[i][6],  st[i][7]) };
          Bfr[2*i+1] = (u32x4){ cvtpk(st[i][8],  st[i][9]),  cvtpk(st[i][10], st[i][11]),
                                cvtpk(st[i][12], st[i][13]), cvtpk(st[i][14], st[i][15]) };
        }

        __builtin_amdgcn_s_setprio(1);
        #pragma unroll
        for (int ss=0; ss<4; ++ss){
          bf16x8 pb = __builtin_bit_cast(bf16x8, Bfr[ss]);
          #pragma unroll
          for (int f=0; f<2; ++f){
            int row = f*32 + l31;
            int colb = (ss*32 + hi*16) ^ ((row & 7) << 4);
            bf16x8 vf = *(const bf16x8*)(Vc + row*128 + colb);
            o[f] = __builtin_amdgcn_mfma_f32_32x32x16_bf16(vf, pb, o[f], 0,0,0);
          }
        }
        __builtin_amdgcn_s_setprio(0);
      }
      __syncthreads();
    }

    float linv = 1.f / l_run;
    {
      char* Osh = (char*)smem;
      unsigned base = wq*4352;
      #pragma unroll
      for (int f=0;f<2;++f)
        #pragma unroll
        for (int m=0;m<8;++m){
          unsigned word = cvtpk(o[f][2*m]*linv, o[f][2*m+1]*linv);
          int d0 = (m&1)*2 + 8*(m>>1) + 4*hi + 32*f;
          *(unsigned*)(Osh + base + l31*136 + d0*2) = word;
        }
    }
    __syncthreads();
    {
      int q = tid >> 1, half = tid & 1;
      const char* src = (const char*)smem + (q>>5)*4352 + (q&31)*136 + half*64;
      u16* dst = AO + ((size_t)(b_*T_LEN + qb + q))*E_DIM + h*D_H + half*32;
      #pragma unroll
      for (int k=0;k<4;++k)
        *(u16x8*)(dst + k*8) = *(const u16x8*)(src + k*16);
    }
  }
}

extern "C" void kernel_launch(void* const* d_in, const int* in_sizes, int n_in,
                              void* d_out, int out_size, void* d_ws, size_t ws_size,
                              hipStream_t stream){
  const float* query = (const float*)d_in[0];
  const float* key   = (const float*)d_in[1];
  const float* value = (const float*)d_in[2];
  const float* Wq = (const float*)d_in[4];
  const float* bq = (const float*)d_in[5];
  const float* Wk = (const float*)d_in[6];
  const float* bk = (const float*)d_in[7];
  const float* Wv = (const float*)d_in[8];
  const float* bv = (const float*)d_in[9];
  const float* Wo = (const float*)d_in[10];
  const float* bo = (const float*)d_in[11];

  char* ws = (char*)d_ws;
  const size_t SZ_X = (size_t)M_ROWS * E_DIM * 2;   // 16 MB
  const size_t SZ_W = (size_t)E_DIM * E_DIM * 2;    // 2 MB
  u16* Xq  = (u16*)(ws);                    // reused as AO after Q-proj
  u16* Xk  = (u16*)(ws + SZ_X);             // reused as Vt after K-proj
  u16* Xv  = (u16*)(ws + 2*SZ_X);
  u16* Wqb = (u16*)(ws + 3*SZ_X);
  u16* Wkb = (u16*)(ws + 3*SZ_X + 1*SZ_W);
  u16* Wvb = (u16*)(ws + 3*SZ_X + 2*SZ_W);
  u16* Wob = (u16*)(ws + 3*SZ_X + 3*SZ_W);
  u16* Qb  = (u16*)(ws + 3*SZ_X + 4*SZ_W);
  u16* Kb  = (u16*)(ws + 4*SZ_X + 4*SZ_W);
  u16* Vb  = (u16*)(ws + 5*SZ_X + 4*SZ_W);
  u16* Vt  = Xk;
  u16* AO  = Xq;

  const int nX = M_ROWS * E_DIM;
  const int nW = E_DIM * E_DIM;
  cvt_all<<<dim3(1024,1,7), 256, 0, stream>>>(
      query, key, value, Wq, Wk, Wv, Wo,
      Xq, Xk, Xv, Wqb, Wkb, Wvb, Wob, nX, nW);

  const float QSCALE = 0.125f * 1.44269504f;   // 1/sqrt(D) * log2(e)
  QKVArgs qa;
  qa.A[0]=Xq;  qa.A[1]=Xk;  qa.A[2]=Xv;
  qa.Bw[0]=Wqb; qa.Bw[1]=Wkb; qa.Bw[2]=Wvb;
  qa.bias[0]=bq; qa.bias[1]=bk; qa.bias[2]=bv;
  qa.scale[0]=QSCALE; qa.scale[1]=1.0f; qa.scale[2]=1.0f;
  qa.out[0]=Qb; qa.out[1]=Kb; qa.out[2]=Vb;
  gemm_qkv<<<dim3(8, M_ROWS/128, 3), 256, 0, stream>>>(qa);
  transpose_v<<<dim3(T_LEN/64, B_SZ*H_N), 256, 0, stream>>>(Vb, Vt);
  attn_fwd<<<dim3(NQT/2, B_SZ*H_N), 256, 0, stream>>>(Qb, Kb, Vt, AO);
  gemm_out<<<dim3(8, M_ROWS/128), 256, 0, stream>>>(AO, Wob, bo, (float*)d_out);
}